// Round 3
// baseline (4649.914 us; speedup 1.0000x reference)
//
#include <hip/hip_runtime.h>
#include <hip/hip_bf16.h>

#define D_MODEL 1024
#define NHEAD 16
#define D_HEAD 64
#define D_FF 4096
#define BATCH 2
#define SEQ 2048
#define M_TOK (BATCH * SEQ)   // 4096 rows
#define EPS 1e-5f

using bf16 = __hip_bfloat16;

__device__ __forceinline__ float b2f(unsigned short u) {
    union { unsigned int i; float f; } v; v.i = ((unsigned int)u) << 16; return v.f;
}
// Dual-path load: p interpreted as float* (f32!=0) or bf16* (f32==0).
__device__ __forceinline__ float loadAt(const void* p, size_t i, int f32) {
    if (f32) return ((const float*)p)[i];
    return b2f(((const unsigned short*)p)[i]);
}

// ---------------------------------------------------------------------------
// Detect input dtype. bf16 N(0,1)-scale data never has exponent >= 0xF0;
// fp32 read as bf16 halfwords has ~6% of low-halves with exp >= 0xF0.
// flag[0] = 1 if inputs are fp32 else 0. flag[1] = 0 always (for bf16 A-paths).
// ---------------------------------------------------------------------------
__global__ void detect_kernel(const unsigned short* __restrict__ x, int* __restrict__ flag) {
    __shared__ int cnt;
    if (threadIdx.x == 0) cnt = 0;
    __syncthreads();
    int c = 0;
    for (int i = threadIdx.x; i < 8192; i += 256) {
        unsigned short u = x[i];
        int e = (u >> 7) & 0xFF;
        if (e >= 0xF0) c++;
    }
    atomicAdd(&cnt, c);
    __syncthreads();
    if (threadIdx.x == 0) { flag[0] = (cnt > 16) ? 1 : 0; flag[1] = 0; }
}

// ---------------------------------------------------------------------------
// GEMM: C[M,N] = A[M,K] @ W[N,K]^T + bias, optional ReLU. fp32 acc, bf16 out.
// 64x64 tile, BK=16, 256 threads, 4x4 per thread.
// aFlagp/wFlagp: dtype flags for A and for W/bias respectively.
// ---------------------------------------------------------------------------
template <bool RELU>
__global__ __launch_bounds__(256) void gemm_bias(
    const void* __restrict__ A, const void* __restrict__ W,
    const void* __restrict__ bias, bf16* __restrict__ C,
    int M, int N, int K,
    const int* __restrict__ aFlagp, const int* __restrict__ wFlagp) {
    const int af = *aFlagp;
    const int wf = *wFlagp;
    __shared__ float As[64][17];
    __shared__ float Bs[64][17];
    const int tid = threadIdx.x;
    const int tx = tid & 15, ty = tid >> 4;
    const int rowBase = blockIdx.y * 64, colBase = blockIdx.x * 64;
    float c[4][4] = {};
    for (int k0 = 0; k0 < K; k0 += 16) {
#pragma unroll
        for (int i = 0; i < 4; i++) {
            int idx = tid + i * 256;
            int r = idx >> 4, cc = idx & 15;
            As[r][cc] = loadAt(A, (size_t)(rowBase + r) * K + k0 + cc, af);
            Bs[r][cc] = loadAt(W, (size_t)(colBase + r) * K + k0 + cc, wf);
        }
        __syncthreads();
#pragma unroll
        for (int kk = 0; kk < 16; kk++) {
            float a[4], b[4];
#pragma unroll
            for (int i = 0; i < 4; i++) a[i] = As[ty * 4 + i][kk];
#pragma unroll
            for (int j = 0; j < 4; j++) b[j] = Bs[tx * 4 + j][kk];
#pragma unroll
            for (int i = 0; i < 4; i++)
#pragma unroll
                for (int j = 0; j < 4; j++) c[i][j] += a[i] * b[j];
        }
        __syncthreads();
    }
#pragma unroll
    for (int i = 0; i < 4; i++) {
        int r = rowBase + ty * 4 + i;
#pragma unroll
        for (int j = 0; j < 4; j++) {
            int cc = colBase + tx * 4 + j;
            float v = c[i][j] + loadAt(bias, cc, wf);
            if (RELU) v = fmaxf(v, 0.0f);
            C[(size_t)r * N + cc] = __float2bfloat16(v);
        }
    }
}

// ---------------------------------------------------------------------------
// Attention: per block handle 4 query rows of one (b,h). Exact softmax.
// Q,K,V bf16 (our own intermediates) in [B,S,H*D] layout. O same layout.
// ---------------------------------------------------------------------------
__global__ __launch_bounds__(256) void attn_kernel(
    const bf16* __restrict__ Q, const bf16* __restrict__ K,
    const bf16* __restrict__ V, bf16* __restrict__ O) {
    const int QR = 4;
    const int bid = blockIdx.x;
    const int qt = bid & 511;            // S/QR = 512
    const int h = (bid >> 9) & 15;
    const int b = bid >> 13;
    const int q0 = qt * QR;
    const int tid = threadIdx.x;

    __shared__ float qs[QR][D_HEAD];
    __shared__ float sc[QR][SEQ];        // 32 KB
    __shared__ float red[256];
    __shared__ float red2[4][QR][D_HEAD];
    __shared__ float rowinv[QR];

    if (tid < QR * D_HEAD) {
        int r = tid >> 6, d = tid & 63;
        qs[r][d] = __bfloat162float(Q[(size_t)(b * SEQ + q0 + r) * D_MODEL + h * D_HEAD + d]);
    }
    __syncthreads();

    // Phase 1: scores
    for (int j = tid; j < SEQ; j += 256) {
        const bf16* kp = K + (size_t)(b * SEQ + j) * D_MODEL + h * D_HEAD;
        float dot[QR] = {0.f, 0.f, 0.f, 0.f};
#pragma unroll 8
        for (int d0 = 0; d0 < D_HEAD; d0++) {
            float kv = __bfloat162float(kp[d0]);
#pragma unroll
            for (int r = 0; r < QR; r++) dot[r] += qs[r][d0] * kv;
        }
#pragma unroll
        for (int r = 0; r < QR; r++) sc[r][j] = dot[r] * 0.125f;
    }
    __syncthreads();

    // Phase 2: softmax per row
    for (int r = 0; r < QR; r++) {
        float m = -1e30f;
        for (int j = tid; j < SEQ; j += 256) m = fmaxf(m, sc[r][j]);
        red[tid] = m; __syncthreads();
        for (int s2 = 128; s2 > 0; s2 >>= 1) {
            if (tid < s2) red[tid] = fmaxf(red[tid], red[tid + s2]);
            __syncthreads();
        }
        m = red[0]; __syncthreads();
        float sum = 0.f;
        for (int j = tid; j < SEQ; j += 256) {
            float p = __expf(sc[r][j] - m);
            sc[r][j] = p;
            sum += p;
        }
        red[tid] = sum; __syncthreads();
        for (int s2 = 128; s2 > 0; s2 >>= 1) {
            if (tid < s2) red[tid] += red[tid + s2];
            __syncthreads();
        }
        if (tid == 0) rowinv[r] = 1.0f / red[0];
        __syncthreads();
    }

    // Phase 3: out = P @ V  (thread d = tid&63, slice = tid>>6 handles 512 j's)
    const int d = tid & 63, slice = tid >> 6;
    float acc[QR] = {0.f, 0.f, 0.f, 0.f};
    const int jEnd = slice * 512 + 512;
    for (int j = slice * 512; j < jEnd; j++) {
        float pv = __bfloat162float(V[(size_t)(b * SEQ + j) * D_MODEL + h * D_HEAD + d]);
#pragma unroll
        for (int r = 0; r < QR; r++) acc[r] += sc[r][j] * pv;
    }
#pragma unroll
    for (int r = 0; r < QR; r++) red2[slice][r][d] = acc[r];
    __syncthreads();
    if (slice == 0) {
#pragma unroll
        for (int r = 0; r < QR; r++) {
            float t = red2[0][r][d] + red2[1][r][d] + red2[2][r][d] + red2[3][r][d];
            O[(size_t)(b * SEQ + q0 + r) * D_MODEL + h * D_HEAD + d] =
                __float2bfloat16(t * rowinv[r]);
        }
    }
}

// ---------------------------------------------------------------------------
// out = LayerNorm(X + R) * g + be  — one block per row of 1024.
// X dtype follows xFlagp; R is always our bf16 intermediate; g/be follow wFlagp.
// OUT_F32 selects fp32 (final output) vs bf16 (intermediate h) store.
// ---------------------------------------------------------------------------
template <bool OUT_F32>
__global__ __launch_bounds__(256) void add_ln_kernel(
    const void* __restrict__ X, const bf16* __restrict__ R,
    const void* __restrict__ g, const void* __restrict__ be,
    void* __restrict__ Y,
    const int* __restrict__ xFlagp, const int* __restrict__ wFlagp) {
    const int xf = *xFlagp;
    const int wf = *wFlagp;
    const int row = blockIdx.x;
    const size_t base = (size_t)row * D_MODEL;
    const int tid = threadIdx.x;
    __shared__ float red[256];
    float v[4];
#pragma unroll
    for (int i = 0; i < 4; i++) {
        int idx = tid + i * 256;
        v[i] = loadAt(X, base + idx, xf) + __bfloat162float(R[base + idx]);
    }
    float s = v[0] + v[1] + v[2] + v[3];
    red[tid] = s; __syncthreads();
    for (int s2 = 128; s2 > 0; s2 >>= 1) {
        if (tid < s2) red[tid] += red[tid + s2];
        __syncthreads();
    }
    float mu = red[0] * (1.0f / D_MODEL);
    __syncthreads();
    float s2v = 0.f;
#pragma unroll
    for (int i = 0; i < 4; i++) { float dd = v[i] - mu; s2v += dd * dd; }
    red[tid] = s2v; __syncthreads();
    for (int s2 = 128; s2 > 0; s2 >>= 1) {
        if (tid < s2) red[tid] += red[tid + s2];
        __syncthreads();
    }
    float rstd = rsqrtf(red[0] * (1.0f / D_MODEL) + EPS);
    __syncthreads();
#pragma unroll
    for (int i = 0; i < 4; i++) {
        int idx = tid + i * 256;
        float o = (v[i] - mu) * rstd * loadAt(g, idx, wf) + loadAt(be, idx, wf);
        if (OUT_F32) ((float*)Y)[base + idx] = o;
        else         ((bf16*)Y)[base + idx] = __float2bfloat16(o);
    }
}

// ---------------------------------------------------------------------------
extern "C" void kernel_launch(void* const* d_in, const int* in_sizes, int n_in,
                              void* d_out, int out_size, void* d_ws, size_t ws_size,
                              hipStream_t stream) {
    const void* x  = d_in[0];
    const void* Wq = d_in[1];  const void* bq = d_in[2];
    const void* Wk = d_in[3];  const void* bk = d_in[4];
    const void* Wv = d_in[5];  const void* bv = d_in[6];
    const void* Wo = d_in[7];  const void* bo = d_in[8];
    const void* W1 = d_in[9];  const void* b1 = d_in[10];
    const void* W2 = d_in[11]; const void* b2 = d_in[12];
    const void* g1 = d_in[13]; const void* be1 = d_in[14];
    const void* g2 = d_in[15]; const void* be2 = d_in[16];

    char* ws = (char*)d_ws;
    const size_t MB = 1024 * 1024;
    bf16* q      = (bf16*)(ws + 0 * MB);    // 8 MB
    bf16* k      = (bf16*)(ws + 8 * MB);    // 8 MB
    bf16* v      = (bf16*)(ws + 16 * MB);   // 8 MB
    bf16* concat = (bf16*)(ws + 24 * MB);   // 8 MB
    bf16* proj   = (bf16*)(ws + 32 * MB);   // 8 MB
    bf16* h      = (bf16*)(ws + 40 * MB);   // 8 MB (live through LN2)
    bf16* ffn1   = (bf16*)(ws + 0 * MB);    // 32 MB (q,k,v,concat dead by then)
    bf16* ffn2   = (bf16*)(ws + 32 * MB);   // 8 MB (proj dead by then)
    int*  flag   = (int*)(ws + 48 * MB);    // flag[0]=input dtype, flag[1]=0

    const int* fIn  = flag;      // dtype of original inputs
    const int* fBf  = flag + 1;  // always 0 => bf16 (our intermediates)

    dim3 blk(256);
    dim3 g1024(D_MODEL / 64, M_TOK / 64);   // (16, 64)
    dim3 g4096(D_FF / 64, M_TOK / 64);      // (64, 64)

    detect_kernel<<<dim3(1), blk, 0, stream>>>((const unsigned short*)x, flag);
    // QKV projections (A = input x, W/bias = inputs)
    gemm_bias<false><<<g1024, blk, 0, stream>>>(x, Wq, bq, q, M_TOK, D_MODEL, D_MODEL, fIn, fIn);
    gemm_bias<false><<<g1024, blk, 0, stream>>>(x, Wk, bk, k, M_TOK, D_MODEL, D_MODEL, fIn, fIn);
    gemm_bias<false><<<g1024, blk, 0, stream>>>(x, Wv, bv, v, M_TOK, D_MODEL, D_MODEL, fIn, fIn);
    // Attention
    attn_kernel<<<dim3(BATCH * NHEAD * (SEQ / 4)), blk, 0, stream>>>(q, k, v, concat);
    // Output projection (A = bf16 intermediate, W/bias = inputs)
    gemm_bias<false><<<g1024, blk, 0, stream>>>(concat, Wo, bo, proj, M_TOK, D_MODEL, D_MODEL, fBf, fIn);
    // Residual + LN1 (X = input x), h is bf16 intermediate
    add_ln_kernel<false><<<dim3(M_TOK), blk, 0, stream>>>(x, proj, g1, be1, h, fIn, fIn);
    // FFN
    gemm_bias<true><<<g4096, blk, 0, stream>>>(h, W1, b1, ffn1, M_TOK, D_FF, D_MODEL, fBf, fIn);
    gemm_bias<false><<<g1024, blk, 0, stream>>>(ffn1, W2, b2, ffn2, M_TOK, D_MODEL, D_FF, fBf, fIn);
    // Residual + LN2 (X = bf16 intermediate h) -> FINAL OUTPUT IS FP32
    add_ln_kernel<true><<<dim3(M_TOK), blk, 0, stream>>>(h, ffn2, g2, be2, d_out, fBf, fIn);
}

// Round 4
// 2383.053 us; speedup vs baseline: 1.9512x; 1.9512x over previous
//
#include <hip/hip_runtime.h>
#include <hip/hip_bf16.h>

#define D_MODEL 1024
#define NHEAD 16
#define D_HEAD 64
#define D_FF 4096
#define BATCH 2
#define SEQ 2048
#define M_TOK (BATCH * SEQ)   // 4096 rows
#define EPS 1e-5f

using bf16 = __hip_bfloat16;
typedef __attribute__((ext_vector_type(8))) short short8;
typedef __attribute__((ext_vector_type(4))) float float4v;

__device__ __forceinline__ float b2f(unsigned short u) {
    union { unsigned int i; float f; } v; v.i = ((unsigned int)u) << 16; return v.f;
}
__device__ __forceinline__ unsigned short f2b(float f) {   // RNE f32->bf16
    union { float f; unsigned int u; } v; v.f = f;
    unsigned int r = v.u + 0x7FFFu + ((v.u >> 16) & 1u);
    return (unsigned short)(r >> 16);
}
// Dual-path scalar load: p is float* (f32!=0) or bf16* (f32==0).
__device__ __forceinline__ float loadAt(const void* p, size_t i, int f32) {
    if (f32) return ((const float*)p)[i];
    return b2f(((const unsigned short*)p)[i]);
}
__device__ __forceinline__ void unpack8(uint4 p, float* f) {
    unsigned int w[4] = {p.x, p.y, p.z, p.w};
#pragma unroll
    for (int i = 0; i < 4; i++) {
        union { unsigned int i_; float f_; } lo, hi;
        lo.i_ = (w[i] & 0xFFFFu) << 16;
        hi.i_ = w[i] & 0xFFFF0000u;
        f[2 * i] = lo.f_; f[2 * i + 1] = hi.f_;
    }
}

// ---------------------------------------------------------------------------
// Detect input dtype. flag[0]=1 if fp32 inputs; flag[1]=0 (bf16 path const).
// ---------------------------------------------------------------------------
__global__ void detect_kernel(const unsigned short* __restrict__ x, int* __restrict__ flag) {
    __shared__ int cnt;
    if (threadIdx.x == 0) cnt = 0;
    __syncthreads();
    int c = 0;
    for (int i = threadIdx.x; i < 8192; i += 256) {
        unsigned short u = x[i];
        int e = (u >> 7) & 0xFF;
        if (e >= 0xF0) c++;
    }
    atomicAdd(&cnt, c);
    __syncthreads();
    if (threadIdx.x == 0) { flag[0] = (cnt > 16) ? 1 : 0; flag[1] = 0; }
}

// ---------------------------------------------------------------------------
// Stage 16 consecutive elements (dual dtype) -> 16 bf16 shorts into LDS.
// ---------------------------------------------------------------------------
__device__ __forceinline__ void stage16(const void* src, size_t elemOff, int f32,
                                        short* ldsDst) {
    short8 lo, hi;
    if (f32) {
        const float* pf = (const float*)src + elemOff;   // 64B-aligned
        float4v f0 = *(const float4v*)(pf + 0);
        float4v f1 = *(const float4v*)(pf + 4);
        float4v f2 = *(const float4v*)(pf + 8);
        float4v f3 = *(const float4v*)(pf + 12);
#pragma unroll
        for (int i = 0; i < 4; i++) { lo[i] = (short)f2b(f0[i]); lo[4 + i] = (short)f2b(f1[i]); }
#pragma unroll
        for (int i = 0; i < 4; i++) { hi[i] = (short)f2b(f2[i]); hi[4 + i] = (short)f2b(f3[i]); }
    } else {
        const short* ps = (const short*)src + elemOff;   // 32B-aligned
        lo = *(const short8*)(ps + 0);
        hi = *(const short8*)(ps + 8);
    }
    *(short8*)(ldsDst + 0) = lo;
    *(short8*)(ldsDst + 8) = hi;
}

// ---------------------------------------------------------------------------
// MFMA GEMM: C[M,N] = A[M,K] @ W[N,K]^T + bias (optional ReLU), bf16 out.
// 128x128 tile, BK=32, 256 threads = 4 waves, each wave 64x64 (4x4 MFMA accs).
// A/W staged via dual-dtype VGPR-convert -> ds_write_b128 (m93 structure).
// Fragment pattern per verified m91/m97: frag row = lane&15, k off = quad*8;
// C/D: row = quad*4+reg, col = lane&15.
// ---------------------------------------------------------------------------
template <bool RELU>
__global__ __launch_bounds__(256) void gemm_mfma(
    const void* __restrict__ A, const void* __restrict__ W,
    const void* __restrict__ bias, bf16* __restrict__ C,
    int N, int K,
    const int* __restrict__ aFlagp, const int* __restrict__ wFlagp) {
    const int af = *aFlagp;
    const int wf = *wFlagp;
    __shared__ short As[128 * 32];
    __shared__ short Bs[128 * 32];
    const int tid = threadIdx.x;
    const int lane = tid & 63;
    const int wv = tid >> 6;
    const int wm = wv & 1, wn = wv >> 1;
    const int quad = lane >> 4, lrow = lane & 15;
    const int rowM = blockIdx.y * 128;     // M base
    const int rowN = blockIdx.x * 128;     // N base (W rows)
    const int sRow = tid >> 1, sCol = (tid & 1) * 16;   // staging: 16 elems/thread

    float4v acc[4][4];
    const float4v zero = {0.f, 0.f, 0.f, 0.f};
#pragma unroll
    for (int i = 0; i < 4; i++)
#pragma unroll
        for (int j = 0; j < 4; j++) acc[i][j] = zero;

    for (int k0 = 0; k0 < K; k0 += 32) {
        stage16(A, (size_t)(rowM + sRow) * K + k0 + sCol, af, &As[sRow * 32 + sCol]);
        stage16(W, (size_t)(rowN + sRow) * K + k0 + sCol, wf, &Bs[sRow * 32 + sCol]);
        __syncthreads();
        short8 a_frag[4], b_frag[4];
#pragma unroll
        for (int i = 0; i < 4; i++) {
            a_frag[i] = *(const short8*)&As[(wm * 64 + i * 16 + lrow) * 32 + quad * 8];
            b_frag[i] = *(const short8*)&Bs[(wn * 64 + i * 16 + lrow) * 32 + quad * 8];
        }
#pragma unroll
        for (int i = 0; i < 4; i++)
#pragma unroll
            for (int j = 0; j < 4; j++)
                acc[i][j] = __builtin_amdgcn_mfma_f32_16x16x32_bf16(
                    a_frag[i], b_frag[j], acc[i][j], 0, 0, 0);
        __syncthreads();
    }

    const int mB = rowM + wm * 64, nB = rowN + wn * 64;
    unsigned short* Cu = (unsigned short*)C;
#pragma unroll
    for (int j = 0; j < 4; j++) {
        const int col = nB + j * 16 + lrow;
        const float bv = loadAt(bias, col, wf);
#pragma unroll
        for (int i = 0; i < 4; i++) {
#pragma unroll
            for (int r = 0; r < 4; r++) {
                const int rowg = mB + i * 16 + quad * 4 + r;
                float vv = acc[i][j][r] + bv;
                if (RELU) vv = fmaxf(vv, 0.0f);
                Cu[(size_t)rowg * N + col] = f2b(vv);
            }
        }
    }
}

// ---------------------------------------------------------------------------
// Attention: per block 4 query rows of one (b,h). Exact softmax, fp32 acc.
// Q,K,V bf16 intermediates in [B,S,H*D] layout. Vectorized loads.
// ---------------------------------------------------------------------------
__global__ __launch_bounds__(256) void attn_kernel(
    const bf16* __restrict__ Q, const bf16* __restrict__ K,
    const bf16* __restrict__ V, bf16* __restrict__ O) {
    const int QR = 4;
    const int bid = blockIdx.x;
    const int qt = bid & 511;            // S/QR = 512
    const int h = (bid >> 9) & 15;
    const int b = bid >> 13;
    const int q0 = qt * QR;
    const int tid = threadIdx.x;

    __shared__ float qs[QR][D_HEAD];
    __shared__ float sc[QR][SEQ];        // 32 KB
    __shared__ float red[256];
    __shared__ float red2[8][QR][D_HEAD];  // 8 KB
    __shared__ float rowinv[QR];

    if (tid < QR * D_HEAD) {
        int r = tid >> 6, d = tid & 63;
        qs[r][d] = __bfloat162float(Q[(size_t)(b * SEQ + q0 + r) * D_MODEL + h * D_HEAD + d]);
    }
    __syncthreads();

    // Phase 1: scores (vectorized K loads: 8 bf16 per uint4)
    for (int j = tid; j < SEQ; j += 256) {
        const uint4* kp = (const uint4*)(K + (size_t)(b * SEQ + j) * D_MODEL + h * D_HEAD);
        float dot[QR] = {0.f, 0.f, 0.f, 0.f};
#pragma unroll
        for (int cchunk = 0; cchunk < 8; cchunk++) {
            float kv[8];
            unpack8(kp[cchunk], kv);
            int d0 = cchunk * 8;
#pragma unroll
            for (int e = 0; e < 8; e++)
#pragma unroll
                for (int r = 0; r < QR; r++) dot[r] += qs[r][d0 + e] * kv[e];
        }
#pragma unroll
        for (int r = 0; r < QR; r++) sc[r][j] = dot[r] * 0.125f;
    }
    __syncthreads();

    // Phase 2: softmax per row
    for (int r = 0; r < QR; r++) {
        float m = -1e30f;
        for (int j = tid; j < SEQ; j += 256) m = fmaxf(m, sc[r][j]);
        red[tid] = m; __syncthreads();
        for (int s2 = 128; s2 > 0; s2 >>= 1) {
            if (tid < s2) red[tid] = fmaxf(red[tid], red[tid + s2]);
            __syncthreads();
        }
        m = red[0]; __syncthreads();
        float sum = 0.f;
        for (int j = tid; j < SEQ; j += 256) {
            float p = __expf(sc[r][j] - m);
            sc[r][j] = p;
            sum += p;
        }
        red[tid] = sum; __syncthreads();
        for (int s2 = 128; s2 > 0; s2 >>= 1) {
            if (tid < s2) red[tid] += red[tid + s2];
            __syncthreads();
        }
        if (tid == 0) rowinv[r] = 1.0f / red[0];
        __syncthreads();
    }

    // Phase 3: out = P @ V. Thread covers 2 d's (packed bf16 loads), 8 slices.
    const int d32 = tid & 31, slice = tid >> 5;
    const int d0 = d32 * 2;
    float acc0[QR] = {0.f, 0.f, 0.f, 0.f};
    float acc1[QR] = {0.f, 0.f, 0.f, 0.f};
    const int jEnd = slice * 256 + 256;
    for (int j = slice * 256; j < jEnd; j++) {
        unsigned int pv = *(const unsigned int*)(V + (size_t)(b * SEQ + j) * D_MODEL + h * D_HEAD + d0);
        float v0 = b2f((unsigned short)(pv & 0xFFFFu));
        float v1 = b2f((unsigned short)(pv >> 16));
#pragma unroll
        for (int r = 0; r < QR; r++) { acc0[r] += sc[r][j] * v0; acc1[r] += sc[r][j] * v1; }
    }
#pragma unroll
    for (int r = 0; r < QR; r++) {
        red2[slice][r][d0] = acc0[r];
        red2[slice][r][d0 + 1] = acc1[r];
    }
    __syncthreads();
    if (slice == 0) {
#pragma unroll
        for (int r = 0; r < QR; r++) {
            float t0 = 0.f, t1 = 0.f;
#pragma unroll
            for (int s = 0; s < 8; s++) { t0 += red2[s][r][d0]; t1 += red2[s][r][d0 + 1]; }
            unsigned int packed = (unsigned int)f2b(t0 * rowinv[r]) |
                                  ((unsigned int)f2b(t1 * rowinv[r]) << 16);
            *(unsigned int*)(O + (size_t)(b * SEQ + q0 + r) * D_MODEL + h * D_HEAD + d0) = packed;
        }
    }
}

// ---------------------------------------------------------------------------
// out = LayerNorm(X + R) * g + be  — one block per row of 1024.
// ---------------------------------------------------------------------------
template <bool OUT_F32>
__global__ __launch_bounds__(256) void add_ln_kernel(
    const void* __restrict__ X, const bf16* __restrict__ R,
    const void* __restrict__ g, const void* __restrict__ be,
    void* __restrict__ Y,
    const int* __restrict__ xFlagp, const int* __restrict__ wFlagp) {
    const int xf = *xFlagp;
    const int wf = *wFlagp;
    const int row = blockIdx.x;
    const size_t base = (size_t)row * D_MODEL;
    const int tid = threadIdx.x;
    __shared__ float red[256];
    float v[4];
#pragma unroll
    for (int i = 0; i < 4; i++) {
        int idx = tid + i * 256;
        v[i] = loadAt(X, base + idx, xf) + __bfloat162float(R[base + idx]);
    }
    float s = v[0] + v[1] + v[2] + v[3];
    red[tid] = s; __syncthreads();
    for (int s2 = 128; s2 > 0; s2 >>= 1) {
        if (tid < s2) red[tid] += red[tid + s2];
        __syncthreads();
    }
    float mu = red[0] * (1.0f / D_MODEL);
    __syncthreads();
    float s2v = 0.f;
#pragma unroll
    for (int i = 0; i < 4; i++) { float dd = v[i] - mu; s2v += dd * dd; }
    red[tid] = s2v; __syncthreads();
    for (int s2 = 128; s2 > 0; s2 >>= 1) {
        if (tid < s2) red[tid] += red[tid + s2];
        __syncthreads();
    }
    float rstd = rsqrtf(red[0] * (1.0f / D_MODEL) + EPS);
    __syncthreads();
#pragma unroll
    for (int i = 0; i < 4; i++) {
        int idx = tid + i * 256;
        float o = (v[i] - mu) * rstd * loadAt(g, idx, wf) + loadAt(be, idx, wf);
        if (OUT_F32) ((float*)Y)[base + idx] = o;
        else         ((bf16*)Y)[base + idx] = __float2bfloat16(o);
    }
}

// ---------------------------------------------------------------------------
extern "C" void kernel_launch(void* const* d_in, const int* in_sizes, int n_in,
                              void* d_out, int out_size, void* d_ws, size_t ws_size,
                              hipStream_t stream) {
    const void* x  = d_in[0];
    const void* Wq = d_in[1];  const void* bq = d_in[2];
    const void* Wk = d_in[3];  const void* bk = d_in[4];
    const void* Wv = d_in[5];  const void* bv = d_in[6];
    const void* Wo = d_in[7];  const void* bo = d_in[8];
    const void* W1 = d_in[9];  const void* b1 = d_in[10];
    const void* W2 = d_in[11]; const void* b2 = d_in[12];
    const void* g1 = d_in[13]; const void* be1 = d_in[14];
    const void* g2 = d_in[15]; const void* be2 = d_in[16];

    char* ws = (char*)d_ws;
    const size_t MB = 1024 * 1024;
    bf16* q      = (bf16*)(ws + 0 * MB);    // 8 MB   (dead after attn)
    bf16* k      = (bf16*)(ws + 8 * MB);    // 8 MB   (dead after attn)
    bf16* v      = (bf16*)(ws + 16 * MB);   // 8 MB   (dead after attn)
    bf16* concat = (bf16*)(ws + 24 * MB);   // 8 MB   (dead after proj)
    bf16* proj   = (bf16*)(ws + 32 * MB);   // 8 MB   (dead after LN1)
    bf16* h      = (bf16*)(ws + 0 * MB);    // 8 MB   (reuse q; live thru LN2)
    bf16* ffn1   = (bf16*)(ws + 8 * MB);    // 32 MB  (reuse k,v,concat,proj)
    bf16* ffn2   = (bf16*)(ws + 40 * MB);   // 8 MB
    int*  flag   = (int*)(ws + 48 * MB);    // flag[0]=input dtype, flag[1]=0

    const int* fIn = flag;      // dtype of original inputs (detected)
    const int* fBf = flag + 1;  // always 0 => bf16 (our intermediates)

    dim3 blk(256);
    dim3 g1024(D_MODEL / 128, M_TOK / 128);   // (8, 32)
    dim3 g4096(D_FF / 128, M_TOK / 128);      // (32, 32)

    detect_kernel<<<dim3(1), blk, 0, stream>>>((const unsigned short*)x, flag);
    // QKV projections (A = x, dual dtype; W/bias = inputs)
    gemm_mfma<false><<<g1024, blk, 0, stream>>>(x, Wq, bq, q, D_MODEL, D_MODEL, fIn, fIn);
    gemm_mfma<false><<<g1024, blk, 0, stream>>>(x, Wk, bk, k, D_MODEL, D_MODEL, fIn, fIn);
    gemm_mfma<false><<<g1024, blk, 0, stream>>>(x, Wv, bv, v, D_MODEL, D_MODEL, fIn, fIn);
    // Attention
    attn_kernel<<<dim3(BATCH * NHEAD * (SEQ / 4)), blk, 0, stream>>>(q, k, v, concat);
    // Output projection
    gemm_mfma<false><<<g1024, blk, 0, stream>>>(concat, Wo, bo, proj, D_MODEL, D_MODEL, fBf, fIn);
    // Residual + LN1 (X = original x)
    add_ln_kernel<false><<<dim3(M_TOK), blk, 0, stream>>>(x, proj, g1, be1, h, fIn, fIn);
    // FFN
    gemm_mfma<true><<<g4096, blk, 0, stream>>>(h, W1, b1, ffn1, D_FF, D_MODEL, fBf, fIn);
    gemm_mfma<false><<<g1024, blk, 0, stream>>>(ffn1, W2, b2, ffn2, D_MODEL, D_FF, fBf, fIn);
    // Residual + LN2 -> fp32 final output
    add_ln_kernel<true><<<dim3(M_TOK), blk, 0, stream>>>(h, ffn2, g2, be2, d_out, fBf, fIn);
}

// Round 5
// 759.354 us; speedup vs baseline: 6.1235x; 3.1383x over previous
//
#include <hip/hip_runtime.h>
#include <hip/hip_bf16.h>

#define D_MODEL 1024
#define NHEAD 16
#define D_HEAD 64
#define D_FF 4096
#define BATCH 2
#define SEQ 2048
#define M_TOK (BATCH * SEQ)   // 4096 rows
#define EPS 1e-5f

using bf16 = __hip_bfloat16;
typedef __attribute__((ext_vector_type(8))) short short8;
typedef __attribute__((ext_vector_type(4))) float float4v;

__device__ __forceinline__ float b2f(unsigned short u) {
    union { unsigned int i; float f; } v; v.i = ((unsigned int)u) << 16; return v.f;
}
__device__ __forceinline__ unsigned short f2b(float f) {   // RNE f32->bf16
    union { float f; unsigned int u; } v; v.f = f;
    unsigned int r = v.u + 0x7FFFu + ((v.u >> 16) & 1u);
    return (unsigned short)(r >> 16);
}
// Dual-path scalar load: p is float* (f32!=0) or bf16* (f32==0).
__device__ __forceinline__ float loadAt(const void* p, size_t i, int f32) {
    if (f32) return ((const float*)p)[i];
    return b2f(((const unsigned short*)p)[i]);
}

// ---------------------------------------------------------------------------
// Detect input dtype. flag[0]=1 if fp32 inputs; flag[1]=0 (bf16 path const).
// ---------------------------------------------------------------------------
__global__ void detect_kernel(const unsigned short* __restrict__ x, int* __restrict__ flag) {
    __shared__ int cnt;
    if (threadIdx.x == 0) cnt = 0;
    __syncthreads();
    int c = 0;
    for (int i = threadIdx.x; i < 8192; i += 256) {
        unsigned short u = x[i];
        int e = (u >> 7) & 0xFF;
        if (e >= 0xF0) c++;
    }
    atomicAdd(&cnt, c);
    __syncthreads();
    if (threadIdx.x == 0) { flag[0] = (cnt > 16) ? 1 : 0; flag[1] = 0; }
}

// ---------------------------------------------------------------------------
// Stage 16 consecutive elements (dual dtype) -> 16 bf16 shorts into LDS.
// ---------------------------------------------------------------------------
__device__ __forceinline__ void stage16(const void* src, size_t elemOff, int f32,
                                        short* ldsDst) {
    short8 lo, hi;
    if (f32) {
        const float* pf = (const float*)src + elemOff;
        float4v f0 = *(const float4v*)(pf + 0);
        float4v f1 = *(const float4v*)(pf + 4);
        float4v f2 = *(const float4v*)(pf + 8);
        float4v f3 = *(const float4v*)(pf + 12);
#pragma unroll
        for (int i = 0; i < 4; i++) { lo[i] = (short)f2b(f0[i]); lo[4 + i] = (short)f2b(f1[i]); }
#pragma unroll
        for (int i = 0; i < 4; i++) { hi[i] = (short)f2b(f2[i]); hi[4 + i] = (short)f2b(f3[i]); }
    } else {
        const short* ps = (const short*)src + elemOff;
        lo = *(const short8*)(ps + 0);
        hi = *(const short8*)(ps + 8);
    }
    *(short8*)(ldsDst + 0) = lo;
    *(short8*)(ldsDst + 8) = hi;
}

// ---------------------------------------------------------------------------
// MFMA GEMM: C[M,N] = A[M,K] @ W[N,K]^T + bias (optional ReLU), bf16 out.
// 128x128 tile, BK=32, 256 threads = 4 waves, each wave 64x64 (4x4 MFMA accs).
// LDS row stride 40 shorts (was 32): frag-read bank conflicts 8-way -> ~2-way.
// ---------------------------------------------------------------------------
#define GSTRIDE 40
template <bool RELU>
__global__ __launch_bounds__(256) void gemm_mfma(
    const void* __restrict__ A, const void* __restrict__ W,
    const void* __restrict__ bias, bf16* __restrict__ C,
    int N, int K,
    const int* __restrict__ aFlagp, const int* __restrict__ wFlagp) {
    const int af = *aFlagp;
    const int wf = *wFlagp;
    __shared__ short As[128 * GSTRIDE];
    __shared__ short Bs[128 * GSTRIDE];
    const int tid = threadIdx.x;
    const int lane = tid & 63;
    const int wv = tid >> 6;
    const int wm = wv & 1, wn = wv >> 1;
    const int quad = lane >> 4, lrow = lane & 15;
    const int rowM = blockIdx.y * 128;
    const int rowN = blockIdx.x * 128;
    const int sRow = tid >> 1, sCol = (tid & 1) * 16;

    float4v acc[4][4];
    const float4v zero = {0.f, 0.f, 0.f, 0.f};
#pragma unroll
    for (int i = 0; i < 4; i++)
#pragma unroll
        for (int j = 0; j < 4; j++) acc[i][j] = zero;

    for (int k0 = 0; k0 < K; k0 += 32) {
        stage16(A, (size_t)(rowM + sRow) * K + k0 + sCol, af, &As[sRow * GSTRIDE + sCol]);
        stage16(W, (size_t)(rowN + sRow) * K + k0 + sCol, wf, &Bs[sRow * GSTRIDE + sCol]);
        __syncthreads();
        short8 a_frag[4], b_frag[4];
#pragma unroll
        for (int i = 0; i < 4; i++) {
            a_frag[i] = *(const short8*)&As[(wm * 64 + i * 16 + lrow) * GSTRIDE + quad * 8];
            b_frag[i] = *(const short8*)&Bs[(wn * 64 + i * 16 + lrow) * GSTRIDE + quad * 8];
        }
#pragma unroll
        for (int i = 0; i < 4; i++)
#pragma unroll
            for (int j = 0; j < 4; j++)
                acc[i][j] = __builtin_amdgcn_mfma_f32_16x16x32_bf16(
                    a_frag[i], b_frag[j], acc[i][j], 0, 0, 0);
        __syncthreads();
    }

    const int mB = rowM + wm * 64, nB = rowN + wn * 64;
    unsigned short* Cu = (unsigned short*)C;
#pragma unroll
    for (int j = 0; j < 4; j++) {
        const int col = nB + j * 16 + lrow;
        const float bv = loadAt(bias, col, wf);
#pragma unroll
        for (int i = 0; i < 4; i++) {
#pragma unroll
            for (int r = 0; r < 4; r++) {
                const int rowg = mB + i * 16 + quad * 4 + r;
                float vv = acc[i][j][r] + bv;
                if (RELU) vv = fmaxf(vv, 0.0f);
                Cu[(size_t)rowg * N + col] = f2b(vv);
            }
        }
    }
}

// ---------------------------------------------------------------------------
// MFMA flash attention. One block per (b, h, 64-row Q tile); 1024 blocks.
// Per 64-j tile: stage K rows + V^T into LDS (68-short padded rows),
// QK^T via mfma (Q A-frags in registers), ONLINE SOFTMAX IN REGISTERS
// (row lives in one quad: shfl_xor 1/2/4/8 reductions; m/l in VGPRs),
// P -> LDS (bf16, C-layout -> A-layout round trip, m120), PV via mfma.
// ---------------------------------------------------------------------------
#define ASTRIDE 68
__global__ __launch_bounds__(256) void flash_attn_kernel(
    const bf16* __restrict__ Q, const bf16* __restrict__ K,
    const bf16* __restrict__ V, bf16* __restrict__ O) {
    const int bid = blockIdx.x;
    const int qt = bid & 31;
    const int h  = (bid >> 5) & 15;
    const int b  = bid >> 9;
    const int q0 = qt * 64;
    const int tid = threadIdx.x;
    const int lane = tid & 63;
    const int wv = tid >> 6;
    const int quad = lane >> 4, lrow = lane & 15;

    __shared__ short Ks[64 * ASTRIDE];
    __shared__ short Vt[64 * ASTRIDE];
    __shared__ short Ps[64 * ASTRIDE];

    const size_t headOff = (size_t)h * D_HEAD;

    // Stage Q tile into Ps (temporary), preload A-frags to registers.
    {
        int r = tid >> 2, c0 = (tid & 3) * 16;
        const short* src = (const short*)Q + (size_t)(b * SEQ + q0 + r) * D_MODEL + headOff + c0;
        *(short8*)&Ps[r * ASTRIDE + c0]     = *(const short8*)src;
        *(short8*)&Ps[r * ASTRIDE + c0 + 8] = *(const short8*)(src + 8);
    }
    __syncthreads();
    short8 a_q[2];
    a_q[0] = *(const short8*)&Ps[(wv * 16 + lrow) * ASTRIDE + 0 * 32 + quad * 8];
    a_q[1] = *(const short8*)&Ps[(wv * 16 + lrow) * ASTRIDE + 1 * 32 + quad * 8];

    float4v o_acc[4];
    const float4v zero = {0.f, 0.f, 0.f, 0.f};
#pragma unroll
    for (int dt = 0; dt < 4; dt++) o_acc[dt] = zero;
    float m_r[4] = {-1e30f, -1e30f, -1e30f, -1e30f};
    float l_r[4] = {0.f, 0.f, 0.f, 0.f};

    for (int j0 = 0; j0 < SEQ; j0 += 64) {
        __syncthreads();   // prev-iter Ps/Vt reads done (and Q preload done)
        // Stage K rows (j, d) as-is
        {
            int r = tid >> 2, c0 = (tid & 3) * 16;
            const short* src = (const short*)K + (size_t)(b * SEQ + j0 + r) * D_MODEL + headOff + c0;
            *(short8*)&Ks[r * ASTRIDE + c0]     = *(const short8*)src;
            *(short8*)&Ks[r * ASTRIDE + c0 + 8] = *(const short8*)(src + 8);
        }
        // Stage V transposed: Vt[d][j]
        {
            int j = tid & 63, d0 = (tid >> 6) * 16;
            const short* src = (const short*)V + (size_t)(b * SEQ + j0 + j) * D_MODEL + headOff + d0;
            short8 v0 = *(const short8*)src;
            short8 v1 = *(const short8*)(src + 8);
#pragma unroll
            for (int e = 0; e < 8; e++) Vt[(d0 + e) * ASTRIDE + j] = v0[e];
#pragma unroll
            for (int e = 0; e < 8; e++) Vt[(d0 + 8 + e) * ASTRIDE + j] = v1[e];
        }
        __syncthreads();

        // QK^T: wave's 16 q-rows x 64 j-cols
        float4v s_acc[4];
#pragma unroll
        for (int jn = 0; jn < 4; jn++) s_acc[jn] = zero;
#pragma unroll
        for (int ks = 0; ks < 2; ks++)
#pragma unroll
            for (int jn = 0; jn < 4; jn++) {
                short8 bfr = *(const short8*)&Ks[(jn * 16 + lrow) * ASTRIDE + ks * 32 + quad * 8];
                s_acc[jn] = __builtin_amdgcn_mfma_f32_16x16x32_bf16(a_q[ks], bfr, s_acc[jn], 0, 0, 0);
            }

        // Online softmax in registers. Row r of this quad = wv*16 + quad*4 + r;
        // its 64 cols live across the quad's 16 lanes x 4 jn regs.
        float p[4][4];     // [jn][r]
        float alpha[4];
#pragma unroll
        for (int r = 0; r < 4; r++) {
            float mx = s_acc[0][r];
#pragma unroll
            for (int jn = 1; jn < 4; jn++) mx = fmaxf(mx, s_acc[jn][r]);
            mx *= 0.125f;
            mx = fmaxf(mx, __shfl_xor(mx, 1));
            mx = fmaxf(mx, __shfl_xor(mx, 2));
            mx = fmaxf(mx, __shfl_xor(mx, 4));
            mx = fmaxf(mx, __shfl_xor(mx, 8));
            float mn = fmaxf(m_r[r], mx);
            alpha[r] = __expf(m_r[r] - mn);
            m_r[r] = mn;
            float ps = 0.f;
#pragma unroll
            for (int jn = 0; jn < 4; jn++) {
                float pv = __expf(s_acc[jn][r] * 0.125f - mn);
                p[jn][r] = pv;
                ps += pv;
            }
            ps += __shfl_xor(ps, 1);
            ps += __shfl_xor(ps, 2);
            ps += __shfl_xor(ps, 4);
            ps += __shfl_xor(ps, 8);
            l_r[r] = l_r[r] * alpha[r] + ps;
        }

        // P: C-layout registers -> LDS (bf16) for A-layout reads
#pragma unroll
        for (int jn = 0; jn < 4; jn++)
#pragma unroll
            for (int r = 0; r < 4; r++)
                Ps[(wv * 16 + quad * 4 + r) * ASTRIDE + jn * 16 + lrow] = (short)f2b(p[jn][r]);
        __syncthreads();

        // Rescale O, then PV
#pragma unroll
        for (int dt = 0; dt < 4; dt++)
#pragma unroll
            for (int r = 0; r < 4; r++) o_acc[dt][r] *= alpha[r];
#pragma unroll
        for (int ks = 0; ks < 2; ks++) {
            short8 pa = *(const short8*)&Ps[(wv * 16 + lrow) * ASTRIDE + ks * 32 + quad * 8];
#pragma unroll
            for (int dt = 0; dt < 4; dt++) {
                short8 vb = *(const short8*)&Vt[(dt * 16 + lrow) * ASTRIDE + ks * 32 + quad * 8];
                o_acc[dt] = __builtin_amdgcn_mfma_f32_16x16x32_bf16(pa, vb, o_acc[dt], 0, 0, 0);
            }
        }
    }

    // Epilogue: O = acc / l
    float invl[4];
#pragma unroll
    for (int r = 0; r < 4; r++) invl[r] = 1.0f / l_r[r];
    unsigned short* Ou = (unsigned short*)O;
#pragma unroll
    for (int dt = 0; dt < 4; dt++)
#pragma unroll
        for (int r = 0; r < 4; r++) {
            const int rowg = b * SEQ + q0 + wv * 16 + quad * 4 + r;
            Ou[(size_t)rowg * D_MODEL + headOff + dt * 16 + lrow] = f2b(o_acc[dt][r] * invl[r]);
        }
}

// ---------------------------------------------------------------------------
// out = LayerNorm(X + R) * g + be  — one block per row of 1024.
// ---------------------------------------------------------------------------
template <bool OUT_F32>
__global__ __launch_bounds__(256) void add_ln_kernel(
    const void* __restrict__ X, const bf16* __restrict__ R,
    const void* __restrict__ g, const void* __restrict__ be,
    void* __restrict__ Y,
    const int* __restrict__ xFlagp, const int* __restrict__ wFlagp) {
    const int xf = *xFlagp;
    const int wf = *wFlagp;
    const int row = blockIdx.x;
    const size_t base = (size_t)row * D_MODEL;
    const int tid = threadIdx.x;
    __shared__ float red[256];
    float v[4];
#pragma unroll
    for (int i = 0; i < 4; i++) {
        int idx = tid + i * 256;
        v[i] = loadAt(X, base + idx, xf) + __bfloat162float(R[base + idx]);
    }
    float s = v[0] + v[1] + v[2] + v[3];
    red[tid] = s; __syncthreads();
    for (int s2 = 128; s2 > 0; s2 >>= 1) {
        if (tid < s2) red[tid] += red[tid + s2];
        __syncthreads();
    }
    float mu = red[0] * (1.0f / D_MODEL);
    __syncthreads();
    float s2v = 0.f;
#pragma unroll
    for (int i = 0; i < 4; i++) { float dd = v[i] - mu; s2v += dd * dd; }
    red[tid] = s2v; __syncthreads();
    for (int s2 = 128; s2 > 0; s2 >>= 1) {
        if (tid < s2) red[tid] += red[tid + s2];
        __syncthreads();
    }
    float rstd = rsqrtf(red[0] * (1.0f / D_MODEL) + EPS);
    __syncthreads();
#pragma unroll
    for (int i = 0; i < 4; i++) {
        int idx = tid + i * 256;
        float o = (v[i] - mu) * rstd * loadAt(g, idx, wf) + loadAt(be, idx, wf);
        if (OUT_F32) ((float*)Y)[base + idx] = o;
        else         ((bf16*)Y)[base + idx] = __float2bfloat16(o);
    }
}

// ---------------------------------------------------------------------------
extern "C" void kernel_launch(void* const* d_in, const int* in_sizes, int n_in,
                              void* d_out, int out_size, void* d_ws, size_t ws_size,
                              hipStream_t stream) {
    const void* x  = d_in[0];
    const void* Wq = d_in[1];  const void* bq = d_in[2];
    const void* Wk = d_in[3];  const void* bk = d_in[4];
    const void* Wv = d_in[5];  const void* bv = d_in[6];
    const void* Wo = d_in[7];  const void* bo = d_in[8];
    const void* W1 = d_in[9];  const void* b1 = d_in[10];
    const void* W2 = d_in[11]; const void* b2 = d_in[12];
    const void* g1 = d_in[13]; const void* be1 = d_in[14];
    const void* g2 = d_in[15]; const void* be2 = d_in[16];

    char* ws = (char*)d_ws;
    const size_t MB = 1024 * 1024;
    bf16* q      = (bf16*)(ws + 0 * MB);    // 8 MB   (dead after attn)
    bf16* k      = (bf16*)(ws + 8 * MB);    // 8 MB   (dead after attn)
    bf16* v      = (bf16*)(ws + 16 * MB);   // 8 MB   (dead after attn)
    bf16* concat = (bf16*)(ws + 24 * MB);   // 8 MB   (dead after proj)
    bf16* proj   = (bf16*)(ws + 32 * MB);   // 8 MB   (dead after LN1)
    bf16* h      = (bf16*)(ws + 0 * MB);    // 8 MB   (reuse q; live thru LN2)
    bf16* ffn1   = (bf16*)(ws + 8 * MB);    // 32 MB  (reuse k,v,concat,proj)
    bf16* ffn2   = (bf16*)(ws + 40 * MB);   // 8 MB
    int*  flag   = (int*)(ws + 48 * MB);    // flag[0]=input dtype, flag[1]=0

    const int* fIn = flag;      // dtype of original inputs (detected)
    const int* fBf = flag + 1;  // always 0 => bf16 (our intermediates)

    dim3 blk(256);
    dim3 g1024(D_MODEL / 128, M_TOK / 128);   // (8, 32)
    dim3 g4096(D_FF / 128, M_TOK / 128);      // (32, 32)

    detect_kernel<<<dim3(1), blk, 0, stream>>>((const unsigned short*)x, flag);
    // QKV projections
    gemm_mfma<false><<<g1024, blk, 0, stream>>>(x, Wq, bq, q, D_MODEL, D_MODEL, fIn, fIn);
    gemm_mfma<false><<<g1024, blk, 0, stream>>>(x, Wk, bk, k, D_MODEL, D_MODEL, fIn, fIn);
    gemm_mfma<false><<<g1024, blk, 0, stream>>>(x, Wv, bv, v, D_MODEL, D_MODEL, fIn, fIn);
    // Flash attention: B*H*(S/64) = 1024 blocks
    flash_attn_kernel<<<dim3(BATCH * NHEAD * (SEQ / 64)), blk, 0, stream>>>(q, k, v, concat);
    // Output projection
    gemm_mfma<false><<<g1024, blk, 0, stream>>>(concat, Wo, bo, proj, D_MODEL, D_MODEL, fBf, fIn);
    // Residual + LN1
    add_ln_kernel<false><<<dim3(M_TOK), blk, 0, stream>>>(x, proj, g1, be1, h, fIn, fIn);
    // FFN
    gemm_mfma<true><<<g4096, blk, 0, stream>>>(h, W1, b1, ffn1, D_FF, D_MODEL, fBf, fIn);
    gemm_mfma<false><<<g1024, blk, 0, stream>>>(ffn1, W2, b2, ffn2, D_MODEL, D_FF, fBf, fIn);
    // Residual + LN2 -> fp32 final output
    add_ln_kernel<true><<<dim3(M_TOK), blk, 0, stream>>>(h, ffn2, g2, be2, d_out, fBf, fIn);
}

// Round 7
// 546.405 us; speedup vs baseline: 8.5100x; 1.3897x over previous
//
#include <hip/hip_runtime.h>
#include <hip/hip_bf16.h>

#define D_MODEL 1024
#define NHEAD 16
#define D_HEAD 64
#define D_FF 4096
#define BATCH 2
#define SEQ 2048
#define M_TOK (BATCH * SEQ)   // 4096 rows
#define EPS 1e-5f
#define QKV_N 3072

using bf16 = __hip_bfloat16;
typedef __attribute__((ext_vector_type(8))) short short8;
typedef __attribute__((ext_vector_type(4))) float float4v;

__device__ __forceinline__ float b2f(unsigned short u) {
    union { unsigned int i; float f; } v; v.i = ((unsigned int)u) << 16; return v.f;
}
__device__ __forceinline__ unsigned short f2b(float f) {   // RNE f32->bf16
    union { float f; unsigned int u; } v; v.f = f;
    unsigned int r = v.u + 0x7FFFu + ((v.u >> 16) & 1u);
    return (unsigned short)(r >> 16);
}
__device__ __forceinline__ float loadAt(const void* p, size_t i, int f32) {
    if (f32) return ((const float*)p)[i];
    return b2f(((const unsigned short*)p)[i]);
}
// Async global->LDS, 16 bytes per lane. LDS dest = wave-uniform base + lane*16.
__device__ __forceinline__ void async16(const void* g, void* lds) {
    __builtin_amdgcn_global_load_lds(
        (const __attribute__((address_space(1))) unsigned int*)g,
        (__attribute__((address_space(3))) unsigned int*)lds, 16, 0, 0);
}

// ---------------------------------------------------------------------------
__global__ void detect_kernel(const unsigned short* __restrict__ x, int* __restrict__ flag) {
    __shared__ int cnt;
    if (threadIdx.x == 0) cnt = 0;
    __syncthreads();
    int c = 0;
    for (int i = threadIdx.x; i < 8192; i += 256) {
        unsigned short u = x[i];
        int e = (u >> 7) & 0xFF;
        if (e >= 0xF0) c++;
    }
    atomicAdd(&cnt, c);
    __syncthreads();
    if (threadIdx.x == 0) { flag[0] = (cnt > 16) ? 1 : 0; flag[1] = 0; }
}

// ---------------------------------------------------------------------------
// Cast n elements (fp32 or bf16 per flag) -> bf16. n % 8 == 0.
// ---------------------------------------------------------------------------
__global__ __launch_bounds__(256) void cast_bf16_kernel(
    const void* __restrict__ src, bf16* __restrict__ dst, int n,
    const int* __restrict__ flagp) {
    const int f32 = *flagp;
    int i0 = (blockIdx.x * 256 + threadIdx.x) * 8;
    if (i0 >= n) return;
    short8 v;
    if (f32) {
        const float* pf = (const float*)src + i0;
        float4v f0 = *(const float4v*)pf;
        float4v f1 = *(const float4v*)(pf + 4);
#pragma unroll
        for (int i = 0; i < 4; i++) { v[i] = (short)f2b(f0[i]); v[4 + i] = (short)f2b(f1[i]); }
    } else {
        v = *(const short8*)((const short*)src + i0);
    }
    *(short8*)((short*)dst + i0) = v;
}

// ---------------------------------------------------------------------------
// Dual-dtype stage of 8 elements -> LDS (for FFN2's original-dtype W2 only).
// ---------------------------------------------------------------------------
__device__ __forceinline__ void stage8(const void* src, size_t off, int f32, short* dst) {
    short8 v;
    if (f32) {
        const float* pf = (const float*)src + off;
        float4v f0 = *(const float4v*)pf;
        float4v f1 = *(const float4v*)(pf + 4);
#pragma unroll
        for (int i = 0; i < 4; i++) { v[i] = (short)f2b(f0[i]); v[4 + i] = (short)f2b(f1[i]); }
    } else {
        v = *(const short8*)((const short*)src + off);
    }
    *(short8*)dst = v;
}

// ---------------------------------------------------------------------------
// MFMA GEMM, m97-style async staging. C[M,N] = A[M,K] @ B[N,K]^T + bias.
// BM=128, BK=32, BN = NF*32. 256 threads = 4 waves as 2x2; wave = 64M x NF*16N.
// A bf16 via global_load_lds; B bf16 async unless BDYN (dual-dtype VGPR stage).
// Bias: up to 3 original-dtype pointers with column boundaries nb1/nb2
// (for the fused QKV gemm); single-bias gemms pass nb1=nb2=N.
// ---------------------------------------------------------------------------
template <int NF, bool RELU, bool BDYN>
__global__ __launch_bounds__(256) void gemm_mfma(
    const bf16* __restrict__ A, const void* __restrict__ B,
    const void* __restrict__ bias0, const void* __restrict__ bias1,
    const void* __restrict__ bias2, int nb1, int nb2,
    bf16* __restrict__ C, int N, int K, const int* __restrict__ inFlagp) {
    constexpr int BN = NF * 32;
    __shared__ short As[128 * 32];
    __shared__ short Bs[BN * 32];
    const int tid = threadIdx.x;
    const int lane = tid & 63;
    const int wv = tid >> 6;
    const int wm = wv & 1, wn = wv >> 1;
    const int quad = lane >> 4, lrow = lane & 15;
    const int rowM = blockIdx.y * 128;
    const int rowN = blockIdx.x * BN;
    const int inf = *inFlagp;   // dtype of original inputs (bias always; B if BDYN)

    float4v acc[4][NF];
    const float4v zero = {0.f, 0.f, 0.f, 0.f};
#pragma unroll
    for (int i = 0; i < 4; i++)
#pragma unroll
        for (int j = 0; j < NF; j++) acc[i][j] = zero;

    const int lr4 = lane >> 2, lc8 = (lane & 3) * 8;

    for (int k0 = 0; k0 < K; k0 += 32) {
        // A: 128x32 shorts = 8KB = 2 rounds of (4 waves x 64 lanes x 16B)
#pragma unroll
        for (int rd = 0; rd < 2; rd++) {
            const short* gp = (const short*)A +
                (size_t)(rowM + rd * 64 + wv * 16 + lr4) * K + k0 + lc8;
            async16(gp, &As[rd * 2048 + wv * 512]);
        }
        if (!BDYN) {
#pragma unroll
            for (int rd = 0; rd < NF / 2; rd++) {
                const short* gp = (const short*)B +
                    (size_t)(rowN + rd * 64 + wv * 16 + lr4) * K + k0 + lc8;
                async16(gp, &Bs[rd * 2048 + wv * 512]);
            }
        } else {
            // BN=64 x 32: 2048 els, 8/thread, dual-dtype via VGPR
            stage8(B, (size_t)(rowN + (tid >> 2)) * K + k0 + (tid & 3) * 8, inf, &Bs[tid * 8]);
        }
        __syncthreads();
        short8 a_frag[4], b_frag[NF];
#pragma unroll
        for (int i = 0; i < 4; i++)
            a_frag[i] = *(const short8*)&As[(wm * 64 + i * 16 + lrow) * 32 + quad * 8];
#pragma unroll
        for (int j = 0; j < NF; j++)
            b_frag[j] = *(const short8*)&Bs[(wn * NF * 16 + j * 16 + lrow) * 32 + quad * 8];
#pragma unroll
        for (int i = 0; i < 4; i++)
#pragma unroll
            for (int j = 0; j < NF; j++)
                acc[i][j] = __builtin_amdgcn_mfma_f32_16x16x32_bf16(
                    a_frag[i], b_frag[j], acc[i][j], 0, 0, 0);
        __syncthreads();
    }

    const int mB = rowM + wm * 64, nB = rowN + wn * NF * 16;
    unsigned short* Cu = (unsigned short*)C;
#pragma unroll
    for (int j = 0; j < NF; j++) {
        const int col = nB + j * 16 + lrow;
        float bv;
        if (col < nb1)      bv = loadAt(bias0, col, inf);
        else if (col < nb2) bv = loadAt(bias1, col - nb1, inf);
        else                bv = loadAt(bias2, col - nb2, inf);
#pragma unroll
        for (int i = 0; i < 4; i++) {
#pragma unroll
            for (int r = 0; r < 4; r++) {
                const int rowg = mB + i * 16 + quad * 4 + r;
                float vv = acc[i][j][r] + bv;
                if (RELU) vv = fmaxf(vv, 0.0f);
                Cu[(size_t)rowg * N + col] = f2b(vv);
            }
        }
    }
}

// ---------------------------------------------------------------------------
// MFMA flash attention (verified R5 structure). Q/K/V read from fused qkv
// buffer with row stride QKV_N; O written at stride D_MODEL.
// ---------------------------------------------------------------------------
#define ASTRIDE 68
__global__ __launch_bounds__(256) void flash_attn_kernel(
    const bf16* __restrict__ Qb, const bf16* __restrict__ Kb,
    const bf16* __restrict__ Vb, bf16* __restrict__ O) {
    const int bid = blockIdx.x;
    const int qt = bid & 31;
    const int h  = (bid >> 5) & 15;
    const int b  = bid >> 9;
    const int q0 = qt * 64;
    const int tid = threadIdx.x;
    const int lane = tid & 63;
    const int wv = tid >> 6;
    const int quad = lane >> 4, lrow = lane & 15;

    __shared__ short Ks[64 * ASTRIDE];
    __shared__ short Vt[64 * ASTRIDE];
    __shared__ short Ps[64 * ASTRIDE];

    const size_t headOff = (size_t)h * D_HEAD;

    {
        int r = tid >> 2, c0 = (tid & 3) * 16;
        const short* src = (const short*)Qb + (size_t)(b * SEQ + q0 + r) * QKV_N + headOff + c0;
        *(short8*)&Ps[r * ASTRIDE + c0]     = *(const short8*)src;
        *(short8*)&Ps[r * ASTRIDE + c0 + 8] = *(const short8*)(src + 8);
    }
    __syncthreads();
    short8 a_q[2];
    a_q[0] = *(const short8*)&Ps[(wv * 16 + lrow) * ASTRIDE + 0 * 32 + quad * 8];
    a_q[1] = *(const short8*)&Ps[(wv * 16 + lrow) * ASTRIDE + 1 * 32 + quad * 8];

    float4v o_acc[4];
    const float4v zero = {0.f, 0.f, 0.f, 0.f};
#pragma unroll
    for (int dt = 0; dt < 4; dt++) o_acc[dt] = zero;
    float m_r[4] = {-1e30f, -1e30f, -1e30f, -1e30f};
    float l_r[4] = {0.f, 0.f, 0.f, 0.f};

    for (int j0 = 0; j0 < SEQ; j0 += 64) {
        __syncthreads();
        {
            int r = tid >> 2, c0 = (tid & 3) * 16;
            const short* src = (const short*)Kb + (size_t)(b * SEQ + j0 + r) * QKV_N + headOff + c0;
            *(short8*)&Ks[r * ASTRIDE + c0]     = *(const short8*)src;
            *(short8*)&Ks[r * ASTRIDE + c0 + 8] = *(const short8*)(src + 8);
        }
        {
            int j = tid & 63, d0 = (tid >> 6) * 16;
            const short* src = (const short*)Vb + (size_t)(b * SEQ + j0 + j) * QKV_N + headOff + d0;
            short8 v0 = *(const short8*)src;
            short8 v1 = *(const short8*)(src + 8);
#pragma unroll
            for (int e = 0; e < 8; e++) Vt[(d0 + e) * ASTRIDE + j] = v0[e];
#pragma unroll
            for (int e = 0; e < 8; e++) Vt[(d0 + 8 + e) * ASTRIDE + j] = v1[e];
        }
        __syncthreads();

        float4v s_acc[4];
#pragma unroll
        for (int jn = 0; jn < 4; jn++) s_acc[jn] = zero;
#pragma unroll
        for (int ks = 0; ks < 2; ks++)
#pragma unroll
            for (int jn = 0; jn < 4; jn++) {
                short8 bfr = *(const short8*)&Ks[(jn * 16 + lrow) * ASTRIDE + ks * 32 + quad * 8];
                s_acc[jn] = __builtin_amdgcn_mfma_f32_16x16x32_bf16(a_q[ks], bfr, s_acc[jn], 0, 0, 0);
            }

        float p[4][4];
        float alpha[4];
#pragma unroll
        for (int r = 0; r < 4; r++) {
            float mx = s_acc[0][r];
#pragma unroll
            for (int jn = 1; jn < 4; jn++) mx = fmaxf(mx, s_acc[jn][r]);
            mx *= 0.125f;
            mx = fmaxf(mx, __shfl_xor(mx, 1));
            mx = fmaxf(mx, __shfl_xor(mx, 2));
            mx = fmaxf(mx, __shfl_xor(mx, 4));
            mx = fmaxf(mx, __shfl_xor(mx, 8));
            float mn = fmaxf(m_r[r], mx);
            alpha[r] = __expf(m_r[r] - mn);
            m_r[r] = mn;
            float ps = 0.f;
#pragma unroll
            for (int jn = 0; jn < 4; jn++) {
                float pv = __expf(s_acc[jn][r] * 0.125f - mn);
                p[jn][r] = pv;
                ps += pv;
            }
            ps += __shfl_xor(ps, 1);
            ps += __shfl_xor(ps, 2);
            ps += __shfl_xor(ps, 4);
            ps += __shfl_xor(ps, 8);
            l_r[r] = l_r[r] * alpha[r] + ps;
        }

#pragma unroll
        for (int jn = 0; jn < 4; jn++)
#pragma unroll
            for (int r = 0; r < 4; r++)
                Ps[(wv * 16 + quad * 4 + r) * ASTRIDE + jn * 16 + lrow] = (short)f2b(p[jn][r]);
        __syncthreads();

#pragma unroll
        for (int dt = 0; dt < 4; dt++)
#pragma unroll
            for (int r = 0; r < 4; r++) o_acc[dt][r] *= alpha[r];
#pragma unroll
        for (int ks = 0; ks < 2; ks++) {
            short8 pa = *(const short8*)&Ps[(wv * 16 + lrow) * ASTRIDE + ks * 32 + quad * 8];
#pragma unroll
            for (int dt = 0; dt < 4; dt++) {
                short8 vb = *(const short8*)&Vt[(dt * 16 + lrow) * ASTRIDE + ks * 32 + quad * 8];
                o_acc[dt] = __builtin_amdgcn_mfma_f32_16x16x32_bf16(pa, vb, o_acc[dt], 0, 0, 0);
            }
        }
    }

    float invl[4];
#pragma unroll
    for (int r = 0; r < 4; r++) invl[r] = 1.0f / l_r[r];
    unsigned short* Ou = (unsigned short*)O;
#pragma unroll
    for (int dt = 0; dt < 4; dt++)
#pragma unroll
        for (int r = 0; r < 4; r++) {
            const int rowg = b * SEQ + q0 + wv * 16 + quad * 4 + r;
            Ou[(size_t)rowg * D_MODEL + headOff + dt * 16 + lrow] = f2b(o_acc[dt][r] * invl[r]);
        }
}

// ---------------------------------------------------------------------------
// out = LayerNorm(X + R) * g + be  — one block per row of 1024.
// ---------------------------------------------------------------------------
template <bool OUT_F32>
__global__ __launch_bounds__(256) void add_ln_kernel(
    const void* __restrict__ X, const bf16* __restrict__ R,
    const void* __restrict__ g, const void* __restrict__ be,
    void* __restrict__ Y,
    const int* __restrict__ xFlagp, const int* __restrict__ wFlagp) {
    const int xf = *xFlagp;
    const int wf = *wFlagp;
    const int row = blockIdx.x;
    const size_t base = (size_t)row * D_MODEL;
    const int tid = threadIdx.x;
    __shared__ float red[256];
    float v[4];
#pragma unroll
    for (int i = 0; i < 4; i++) {
        int idx = tid + i * 256;
        v[i] = loadAt(X, base + idx, xf) + __bfloat162float(R[base + idx]);
    }
    float s = v[0] + v[1] + v[2] + v[3];
    red[tid] = s; __syncthreads();
    for (int s2 = 128; s2 > 0; s2 >>= 1) {
        if (tid < s2) red[tid] += red[tid + s2];
        __syncthreads();
    }
    float mu = red[0] * (1.0f / D_MODEL);
    __syncthreads();
    float s2v = 0.f;
#pragma unroll
    for (int i = 0; i < 4; i++) { float dd = v[i] - mu; s2v += dd * dd; }
    red[tid] = s2v; __syncthreads();
    for (int s2 = 128; s2 > 0; s2 >>= 1) {
        if (tid < s2) red[tid] += red[tid + s2];
        __syncthreads();
    }
    float rstd = rsqrtf(red[0] * (1.0f / D_MODEL) + EPS);
    __syncthreads();
#pragma unroll
    for (int i = 0; i < 4; i++) {
        int idx = tid + i * 256;
        float o = (v[i] - mu) * rstd * loadAt(g, idx, wf) + loadAt(be, idx, wf);
        if (OUT_F32) ((float*)Y)[base + idx] = o;
        else         ((bf16*)Y)[base + idx] = __float2bfloat16(o);
    }
}

// ---------------------------------------------------------------------------
extern "C" void kernel_launch(void* const* d_in, const int* in_sizes, int n_in,
                              void* d_out, int out_size, void* d_ws, size_t ws_size,
                              hipStream_t stream) {
    const void* x  = d_in[0];
    const void* Wq = d_in[1];  const void* bq = d_in[2];
    const void* Wk = d_in[3];  const void* bk = d_in[4];
    const void* Wv = d_in[5];  const void* bv = d_in[6];
    const void* Wo = d_in[7];  const void* bo = d_in[8];
    const void* W1 = d_in[9];  const void* b1 = d_in[10];
    const void* W2 = d_in[11]; const void* b2 = d_in[12];
    const void* g1 = d_in[13]; const void* be1 = d_in[14];
    const void* g2 = d_in[15]; const void* be2 = d_in[16];

    char* ws = (char*)d_ws;
    const size_t MB = 1024 * 1024;
    // Workspace choreography — no overlaps at any launch point:
    //  [0..8)   xb        (cast -> QKV gemm)
    //  [8..14)  wqkvb     (cast -> QKV gemm)
    //  [14..16) wob       (cast -> Wo gemm)
    //  [16..40) qkv       (QKV gemm -> flash)
    //  [40..48) concat    (flash -> Wo gemm)
    //  [0..8)   w1b       (cast after QKV -> FFN1)
    //  [16..24) proj      (Wo gemm -> LN1)
    //  [8..16)  hb        (LN1 -> LN2)          [wqkvb,wob dead]
    //  [16..48) ffn1      (FFN1 -> FFN2)        [proj,qkv,concat dead]
    //  [0..8)   ffn2      (FFN2 -> LN2)         [w1b dead]
    //  48MB     flag (8 B)
    bf16* xb     = (bf16*)(ws + 0 * MB);
    bf16* wqkvb  = (bf16*)(ws + 8 * MB);
    bf16* wob    = (bf16*)(ws + 14 * MB);
    bf16* qkv    = (bf16*)(ws + 16 * MB);
    bf16* concat = (bf16*)(ws + 40 * MB);
    bf16* w1b    = (bf16*)(ws + 0 * MB);
    bf16* proj   = (bf16*)(ws + 16 * MB);
    bf16* hb     = (bf16*)(ws + 8 * MB);
    bf16* ffn1   = (bf16*)(ws + 16 * MB);
    bf16* ffn2   = (bf16*)(ws + 0 * MB);
    int*  flag   = (int*)(ws + 48 * MB);

    const int* fIn = flag;
    const int* fBf = flag + 1;

    dim3 blk(256);

    detect_kernel<<<dim3(1), blk, 0, stream>>>((const unsigned short*)x, flag);
    // Pre-cast x and QKV weights
    cast_bf16_kernel<<<dim3((M_TOK * D_MODEL / 8 + 255) / 256), blk, 0, stream>>>(x, xb, M_TOK * D_MODEL, fIn);
    cast_bf16_kernel<<<dim3((D_MODEL * D_MODEL / 8 + 255) / 256), blk, 0, stream>>>(Wq, wqkvb, D_MODEL * D_MODEL, fIn);
    cast_bf16_kernel<<<dim3((D_MODEL * D_MODEL / 8 + 255) / 256), blk, 0, stream>>>(Wk, wqkvb + D_MODEL * D_MODEL, D_MODEL * D_MODEL, fIn);
    cast_bf16_kernel<<<dim3((D_MODEL * D_MODEL / 8 + 255) / 256), blk, 0, stream>>>(Wv, wqkvb + 2 * D_MODEL * D_MODEL, D_MODEL * D_MODEL, fIn);
    // Fused QKV projection: [4096,3072] = xb @ wqkvb^T  (3-way bias select)
    gemm_mfma<4, false, false><<<dim3(QKV_N / 128, M_TOK / 128), blk, 0, stream>>>(
        xb, wqkvb, bq, bk, bv, 1024, 2048, qkv, QKV_N, D_MODEL, fIn);
    // Cast Wo/W1 into regions freed by xb/wqkvb
    cast_bf16_kernel<<<dim3((D_MODEL * D_MODEL / 8 + 255) / 256), blk, 0, stream>>>(Wo, wob, D_MODEL * D_MODEL, fIn);
    cast_bf16_kernel<<<dim3((D_FF * D_MODEL / 8 + 255) / 256), blk, 0, stream>>>(W1, w1b, D_FF * D_MODEL, fIn);
    // Flash attention over fused qkv
    flash_attn_kernel<<<dim3(BATCH * NHEAD * (SEQ / 64)), blk, 0, stream>>>(
        qkv, qkv + D_MODEL, qkv + 2 * D_MODEL, concat);
    // Output projection (BN=64 -> 512 blocks)
    gemm_mfma<2, false, false><<<dim3(D_MODEL / 64, M_TOK / 128), blk, 0, stream>>>(
        concat, wob, bo, bo, bo, D_MODEL, D_MODEL, proj, D_MODEL, D_MODEL, fIn);
    // Residual + LN1
    add_ln_kernel<false><<<dim3(M_TOK), blk, 0, stream>>>(x, proj, g1, be1, hb, fIn, fIn);
    // FFN1 (BN=128 -> 1024 blocks, ReLU)
    gemm_mfma<4, true, false><<<dim3(D_FF / 128, M_TOK / 128), blk, 0, stream>>>(
        hb, w1b, b1, b1, b1, D_FF, D_FF, ffn1, D_FF, D_MODEL, fIn);
    // FFN2 (BN=64 -> 512 blocks; W2 stays original dtype, dual-staged)
    gemm_mfma<2, false, true><<<dim3(D_MODEL / 64, M_TOK / 128), blk, 0, stream>>>(
        ffn1, W2, b2, b2, b2, D_MODEL, D_MODEL, ffn2, D_MODEL, D_FF, fIn);
    // Residual + LN2 -> fp32 output
    add_ln_kernel<true><<<dim3(M_TOK), blk, 0, stream>>>(hb, ffn2, g2, be2, d_out, fBf, fIn);
}

// Round 8
// 481.405 us; speedup vs baseline: 9.6590x; 1.1350x over previous
//
#include <hip/hip_runtime.h>
#include <hip/hip_bf16.h>

#define D_MODEL 1024
#define NHEAD 16
#define D_HEAD 64
#define D_FF 4096
#define BATCH 2
#define SEQ 2048
#define M_TOK (BATCH * SEQ)   // 4096 rows
#define EPS 1e-5f
#define QKV_N 3072

using bf16 = __hip_bfloat16;
typedef __attribute__((ext_vector_type(8))) short short8;
typedef __attribute__((ext_vector_type(4))) float float4v;

__device__ __forceinline__ float b2f(unsigned short u) {
    union { unsigned int i; float f; } v; v.i = ((unsigned int)u) << 16; return v.f;
}
__device__ __forceinline__ unsigned short f2b(float f) {   // RNE f32->bf16
    union { float f; unsigned int u; } v; v.f = f;
    unsigned int r = v.u + 0x7FFFu + ((v.u >> 16) & 1u);
    return (unsigned short)(r >> 16);
}
__device__ __forceinline__ float loadAt(const void* p, size_t i, int f32) {
    if (f32) return ((const float*)p)[i];
    return b2f(((const unsigned short*)p)[i]);
}
// Async global->LDS, 16 bytes per lane. LDS dest = wave-uniform base + lane*16.
__device__ __forceinline__ void async16(const void* g, void* lds) {
    __builtin_amdgcn_global_load_lds(
        (const __attribute__((address_space(1))) unsigned int*)g,
        (__attribute__((address_space(3))) unsigned int*)lds, 16, 0, 0);
}

// ---------------------------------------------------------------------------
__global__ void detect_kernel(const unsigned short* __restrict__ x, int* __restrict__ flag) {
    __shared__ int cnt;
    if (threadIdx.x == 0) cnt = 0;
    __syncthreads();
    int c = 0;
    for (int i = threadIdx.x; i < 8192; i += 256) {
        unsigned short u = x[i];
        int e = (u >> 7) & 0xFF;
        if (e >= 0xF0) c++;
    }
    atomicAdd(&cnt, c);
    __syncthreads();
    if (threadIdx.x == 0) { flag[0] = (cnt > 16) ? 1 : 0; flag[1] = 0; }
}

// ---------------------------------------------------------------------------
// Cast n elements (fp32 or bf16 per flag) -> bf16. n % 8 == 0.
// ---------------------------------------------------------------------------
__global__ __launch_bounds__(256) void cast_bf16_kernel(
    const void* __restrict__ src, bf16* __restrict__ dst, int n,
    const int* __restrict__ flagp) {
    const int f32 = *flagp;
    int i0 = (blockIdx.x * 256 + threadIdx.x) * 8;
    if (i0 >= n) return;
    short8 v;
    if (f32) {
        const float* pf = (const float*)src + i0;
        float4v f0 = *(const float4v*)pf;
        float4v f1 = *(const float4v*)(pf + 4);
#pragma unroll
        for (int i = 0; i < 4; i++) { v[i] = (short)f2b(f0[i]); v[4 + i] = (short)f2b(f1[i]); }
    } else {
        v = *(const short8*)((const short*)src + i0);
    }
    *(short8*)((short*)dst + i0) = v;
}

// ---------------------------------------------------------------------------
// Cast 3 equal-size sources into one contiguous bf16 dst (QKV weights).
// Each part = D_MODEL*D_MODEL = 2^20 elements.
// ---------------------------------------------------------------------------
__global__ __launch_bounds__(256) void cast3_bf16_kernel(
    const void* __restrict__ s0, const void* __restrict__ s1,
    const void* __restrict__ s2, bf16* __restrict__ dst,
    const int* __restrict__ flagp) {
    const int f32 = *flagp;
    int i0 = (blockIdx.x * 256 + threadIdx.x) * 8;
    const int part = i0 >> 20;
    const int off = i0 & ((1 << 20) - 1);
    const void* src = (part == 0) ? s0 : (part == 1) ? s1 : s2;
    short8 v;
    if (f32) {
        const float* pf = (const float*)src + off;
        float4v f0 = *(const float4v*)pf;
        float4v f1 = *(const float4v*)(pf + 4);
#pragma unroll
        for (int i = 0; i < 4; i++) { v[i] = (short)f2b(f0[i]); v[4 + i] = (short)f2b(f1[i]); }
    } else {
        v = *(const short8*)((const short*)src + off);
    }
    *(short8*)((short*)dst + i0) = v;
}

// ---------------------------------------------------------------------------
// Dual-dtype stage of 8 elements -> LDS (for FFN2's original-dtype W2 only).
// ---------------------------------------------------------------------------
__device__ __forceinline__ void stage8(const void* src, size_t off, int f32, short* dst) {
    short8 v;
    if (f32) {
        const float* pf = (const float*)src + off;
        float4v f0 = *(const float4v*)pf;
        float4v f1 = *(const float4v*)(pf + 4);
#pragma unroll
        for (int i = 0; i < 4; i++) { v[i] = (short)f2b(f0[i]); v[4 + i] = (short)f2b(f1[i]); }
    } else {
        v = *(const short8*)((const short*)src + off);
    }
    *(short8*)dst = v;
}

// ---------------------------------------------------------------------------
// MFMA GEMM, m97-style async staging. C[M,N] = A[M,K] @ B[N,K]^T + bias.
// BM=128, BK=32, BN = NF*32. 256 threads = 4 waves as 2x2; wave = 64M x NF*16N.
// ---------------------------------------------------------------------------
template <int NF, bool RELU, bool BDYN>
__global__ __launch_bounds__(256) void gemm_mfma(
    const bf16* __restrict__ A, const void* __restrict__ B,
    const void* __restrict__ bias0, const void* __restrict__ bias1,
    const void* __restrict__ bias2, int nb1, int nb2,
    bf16* __restrict__ C, int N, int K, const int* __restrict__ inFlagp) {
    constexpr int BN = NF * 32;
    __shared__ short As[128 * 32];
    __shared__ short Bs[BN * 32];
    const int tid = threadIdx.x;
    const int lane = tid & 63;
    const int wv = tid >> 6;
    const int wm = wv & 1, wn = wv >> 1;
    const int quad = lane >> 4, lrow = lane & 15;
    const int rowM = blockIdx.y * 128;
    const int rowN = blockIdx.x * BN;
    const int inf = *inFlagp;

    float4v acc[4][NF];
    const float4v zero = {0.f, 0.f, 0.f, 0.f};
#pragma unroll
    for (int i = 0; i < 4; i++)
#pragma unroll
        for (int j = 0; j < NF; j++) acc[i][j] = zero;

    const int lr4 = lane >> 2, lc8 = (lane & 3) * 8;

    for (int k0 = 0; k0 < K; k0 += 32) {
#pragma unroll
        for (int rd = 0; rd < 2; rd++) {
            const short* gp = (const short*)A +
                (size_t)(rowM + rd * 64 + wv * 16 + lr4) * K + k0 + lc8;
            async16(gp, &As[rd * 2048 + wv * 512]);
        }
        if (!BDYN) {
#pragma unroll
            for (int rd = 0; rd < NF / 2; rd++) {
                const short* gp = (const short*)B +
                    (size_t)(rowN + rd * 64 + wv * 16 + lr4) * K + k0 + lc8;
                async16(gp, &Bs[rd * 2048 + wv * 512]);
            }
        } else {
            stage8(B, (size_t)(rowN + (tid >> 2)) * K + k0 + (tid & 3) * 8, inf, &Bs[tid * 8]);
        }
        __syncthreads();
        short8 a_frag[4], b_frag[NF];
#pragma unroll
        for (int i = 0; i < 4; i++)
            a_frag[i] = *(const short8*)&As[(wm * 64 + i * 16 + lrow) * 32 + quad * 8];
#pragma unroll
        for (int j = 0; j < NF; j++)
            b_frag[j] = *(const short8*)&Bs[(wn * NF * 16 + j * 16 + lrow) * 32 + quad * 8];
#pragma unroll
        for (int i = 0; i < 4; i++)
#pragma unroll
            for (int j = 0; j < NF; j++)
                acc[i][j] = __builtin_amdgcn_mfma_f32_16x16x32_bf16(
                    a_frag[i], b_frag[j], acc[i][j], 0, 0, 0);
        __syncthreads();
    }

    const int mB = rowM + wm * 64, nB = rowN + wn * NF * 16;
    unsigned short* Cu = (unsigned short*)C;
#pragma unroll
    for (int j = 0; j < NF; j++) {
        const int col = nB + j * 16 + lrow;
        float bv;
        if (col < nb1)      bv = loadAt(bias0, col, inf);
        else if (col < nb2) bv = loadAt(bias1, col - nb1, inf);
        else                bv = loadAt(bias2, col - nb2, inf);
#pragma unroll
        for (int i = 0; i < 4; i++) {
#pragma unroll
            for (int r = 0; r < 4; r++) {
                const int rowg = mB + i * 16 + quad * 4 + r;
                float vv = acc[i][j][r] + bv;
                if (RELU) vv = fmaxf(vv, 0.0f);
                Cu[(size_t)rowg * N + col] = f2b(vv);
            }
        }
    }
}

// ---------------------------------------------------------------------------
// MFMA flash attention, fixed-max softmax.
//   p = exp2(s*0.125*log2e - 16*log2e)  — the 16 cancels in O = Σpv/Σp.
// No max reduction, no rescale, no in-loop shuffles: per-lane l partials,
// one quad-reduction at the end. V transposed via b32-packed LDS writes.
// ---------------------------------------------------------------------------
#define ASTRIDE 68
__global__ __launch_bounds__(256) void flash_attn_kernel(
    const bf16* __restrict__ Qb, const bf16* __restrict__ Kb,
    const bf16* __restrict__ Vb, bf16* __restrict__ O) {
    const int bid = blockIdx.x;
    const int qt = bid & 31;
    const int h  = (bid >> 5) & 15;
    const int b  = bid >> 9;
    const int q0 = qt * 64;
    const int tid = threadIdx.x;
    const int lane = tid & 63;
    const int wv = tid >> 6;
    const int quad = lane >> 4, lrow = lane & 15;

    __shared__ short Ks[64 * ASTRIDE];
    __shared__ short Vt[64 * ASTRIDE];
    __shared__ short Ps[64 * ASTRIDE];

    const size_t headOff = (size_t)h * D_HEAD;
    const float SC = 0.18033688f;    // 0.125 * log2(e)
    const float M2 = 23.0831204f;    // 16 * log2(e)

    {
        int r = tid >> 2, c0 = (tid & 3) * 16;
        const short* src = (const short*)Qb + (size_t)(b * SEQ + q0 + r) * QKV_N + headOff + c0;
        *(short8*)&Ps[r * ASTRIDE + c0]     = *(const short8*)src;
        *(short8*)&Ps[r * ASTRIDE + c0 + 8] = *(const short8*)(src + 8);
    }
    __syncthreads();
    short8 a_q[2];
    a_q[0] = *(const short8*)&Ps[(wv * 16 + lrow) * ASTRIDE + 0 * 32 + quad * 8];
    a_q[1] = *(const short8*)&Ps[(wv * 16 + lrow) * ASTRIDE + 1 * 32 + quad * 8];

    float4v o_acc[4];
    const float4v zero = {0.f, 0.f, 0.f, 0.f};
#pragma unroll
    for (int dt = 0; dt < 4; dt++) o_acc[dt] = zero;
    float lsum[4] = {0.f, 0.f, 0.f, 0.f};

    for (int j0 = 0; j0 < SEQ; j0 += 64) {
        __syncthreads();
        // Stage K rows as-is
        {
            int r = tid >> 2, c0 = (tid & 3) * 16;
            const short* src = (const short*)Kb + (size_t)(b * SEQ + j0 + r) * QKV_N + headOff + c0;
            *(short8*)&Ks[r * ASTRIDE + c0]     = *(const short8*)src;
            *(short8*)&Ks[r * ASTRIDE + c0 + 8] = *(const short8*)(src + 8);
        }
        // Stage V transposed: b32-packed (2 j's per write)
        {
            int jp = (tid & 31) * 2, d0 = (tid >> 5) * 8;
            const short* s0 = (const short*)Vb + (size_t)(b * SEQ + j0 + jp) * QKV_N + headOff + d0;
            short8 v0 = *(const short8*)s0;
            short8 v1 = *(const short8*)(s0 + QKV_N);
#pragma unroll
            for (int e = 0; e < 8; e++) {
                unsigned int w = (unsigned int)(unsigned short)v0[e] |
                                 ((unsigned int)(unsigned short)v1[e] << 16);
                *(unsigned int*)&Vt[(d0 + e) * ASTRIDE + jp] = w;
            }
        }
        __syncthreads();

        // QK^T
        float4v s_acc[4];
#pragma unroll
        for (int jn = 0; jn < 4; jn++) s_acc[jn] = zero;
#pragma unroll
        for (int ks = 0; ks < 2; ks++)
#pragma unroll
            for (int jn = 0; jn < 4; jn++) {
                short8 bfr = *(const short8*)&Ks[(jn * 16 + lrow) * ASTRIDE + ks * 32 + quad * 8];
                s_acc[jn] = __builtin_amdgcn_mfma_f32_16x16x32_bf16(a_q[ks], bfr, s_acc[jn], 0, 0, 0);
            }

        // Fixed-max softmax: no reductions in the loop
        float p[4][4];
#pragma unroll
        for (int r = 0; r < 4; r++) {
            float ls = 0.f;
#pragma unroll
            for (int jn = 0; jn < 4; jn++) {
                float pv = exp2f(fmaf(s_acc[jn][r], SC, -M2));
                p[jn][r] = pv;
                ls += pv;
            }
            lsum[r] += ls;
        }

        // P: C-layout regs -> LDS bf16 (A-layout round trip)
#pragma unroll
        for (int jn = 0; jn < 4; jn++)
#pragma unroll
            for (int r = 0; r < 4; r++)
                Ps[(wv * 16 + quad * 4 + r) * ASTRIDE + jn * 16 + lrow] = (short)f2b(p[jn][r]);
        __syncthreads();

        // PV (no rescale needed)
#pragma unroll
        for (int ks = 0; ks < 2; ks++) {
            short8 pa = *(const short8*)&Ps[(wv * 16 + lrow) * ASTRIDE + ks * 32 + quad * 8];
#pragma unroll
            for (int dt = 0; dt < 4; dt++) {
                short8 vb = *(const short8*)&Vt[(dt * 16 + lrow) * ASTRIDE + ks * 32 + quad * 8];
                o_acc[dt] = __builtin_amdgcn_mfma_f32_16x16x32_bf16(pa, vb, o_acc[dt], 0, 0, 0);
            }
        }
    }

    // End: reduce l across the quad (cols of each row live in 16 lanes)
    float invl[4];
#pragma unroll
    for (int r = 0; r < 4; r++) {
        float t = lsum[r];
        t += __shfl_xor(t, 1);
        t += __shfl_xor(t, 2);
        t += __shfl_xor(t, 4);
        t += __shfl_xor(t, 8);
        invl[r] = 1.0f / t;
    }
    unsigned short* Ou = (unsigned short*)O;
#pragma unroll
    for (int dt = 0; dt < 4; dt++)
#pragma unroll
        for (int r = 0; r < 4; r++) {
            const int rowg = b * SEQ + q0 + wv * 16 + quad * 4 + r;
            Ou[(size_t)rowg * D_MODEL + headOff + dt * 16 + lrow] = f2b(o_acc[dt][r] * invl[r]);
        }
}

// ---------------------------------------------------------------------------
// out = LayerNorm(X + R) * g + be  — one block per row of 1024.
// ---------------------------------------------------------------------------
template <bool OUT_F32>
__global__ __launch_bounds__(256) void add_ln_kernel(
    const void* __restrict__ X, const bf16* __restrict__ R,
    const void* __restrict__ g, const void* __restrict__ be,
    void* __restrict__ Y,
    const int* __restrict__ xFlagp, const int* __restrict__ wFlagp) {
    const int xf = *xFlagp;
    const int wf = *wFlagp;
    const int row = blockIdx.x;
    const size_t base = (size_t)row * D_MODEL;
    const int tid = threadIdx.x;
    __shared__ float red[256];
    float v[4];
#pragma unroll
    for (int i = 0; i < 4; i++) {
        int idx = tid + i * 256;
        v[i] = loadAt(X, base + idx, xf) + __bfloat162float(R[base + idx]);
    }
    float s = v[0] + v[1] + v[2] + v[3];
    red[tid] = s; __syncthreads();
    for (int s2 = 128; s2 > 0; s2 >>= 1) {
        if (tid < s2) red[tid] += red[tid + s2];
        __syncthreads();
    }
    float mu = red[0] * (1.0f / D_MODEL);
    __syncthreads();
    float s2v = 0.f;
#pragma unroll
    for (int i = 0; i < 4; i++) { float dd = v[i] - mu; s2v += dd * dd; }
    red[tid] = s2v; __syncthreads();
    for (int s2 = 128; s2 > 0; s2 >>= 1) {
        if (tid < s2) red[tid] += red[tid + s2];
        __syncthreads();
    }
    float rstd = rsqrtf(red[0] * (1.0f / D_MODEL) + EPS);
    __syncthreads();
#pragma unroll
    for (int i = 0; i < 4; i++) {
        int idx = tid + i * 256;
        float o = (v[i] - mu) * rstd * loadAt(g, idx, wf) + loadAt(be, idx, wf);
        if (OUT_F32) ((float*)Y)[base + idx] = o;
        else         ((bf16*)Y)[base + idx] = __float2bfloat16(o);
    }
}

// ---------------------------------------------------------------------------
extern "C" void kernel_launch(void* const* d_in, const int* in_sizes, int n_in,
                              void* d_out, int out_size, void* d_ws, size_t ws_size,
                              hipStream_t stream) {
    const void* x  = d_in[0];
    const void* Wq = d_in[1];  const void* bq = d_in[2];
    const void* Wk = d_in[3];  const void* bk = d_in[4];
    const void* Wv = d_in[5];  const void* bv = d_in[6];
    const void* Wo = d_in[7];  const void* bo = d_in[8];
    const void* W1 = d_in[9];  const void* b1 = d_in[10];
    const void* W2 = d_in[11]; const void* b2 = d_in[12];
    const void* g1 = d_in[13]; const void* be1 = d_in[14];
    const void* g2 = d_in[15]; const void* be2 = d_in[16];

    char* ws = (char*)d_ws;
    const size_t MB = 1024 * 1024;
    // Same proven choreography as R7 (48 MB + 8 B):
    bf16* xb     = (bf16*)(ws + 0 * MB);
    bf16* wqkvb  = (bf16*)(ws + 8 * MB);
    bf16* wob    = (bf16*)(ws + 14 * MB);
    bf16* qkv    = (bf16*)(ws + 16 * MB);
    bf16* concat = (bf16*)(ws + 40 * MB);
    bf16* w1b    = (bf16*)(ws + 0 * MB);
    bf16* proj   = (bf16*)(ws + 16 * MB);
    bf16* hb     = (bf16*)(ws + 8 * MB);
    bf16* ffn1   = (bf16*)(ws + 16 * MB);
    bf16* ffn2   = (bf16*)(ws + 0 * MB);
    int*  flag   = (int*)(ws + 48 * MB);

    const int* fIn = flag;
    const int* fBf = flag + 1;

    dim3 blk(256);

    detect_kernel<<<dim3(1), blk, 0, stream>>>((const unsigned short*)x, flag);
    // Pre-cast x; all three QKV weights in one launch (contiguous dst)
    cast_bf16_kernel<<<dim3((M_TOK * D_MODEL / 8 + 255) / 256), blk, 0, stream>>>(x, xb, M_TOK * D_MODEL, fIn);
    cast3_bf16_kernel<<<dim3(3 * D_MODEL * D_MODEL / 8 / 256), blk, 0, stream>>>(Wq, Wk, Wv, wqkvb, fIn);
    // Fused QKV projection: [4096,3072] = xb @ wqkvb^T  (3-way bias select)
    gemm_mfma<4, false, false><<<dim3(QKV_N / 128, M_TOK / 128), blk, 0, stream>>>(
        xb, wqkvb, bq, bk, bv, 1024, 2048, qkv, QKV_N, D_MODEL, fIn);
    // Cast Wo/W1 into regions freed by xb/wqkvb
    cast_bf16_kernel<<<dim3((D_MODEL * D_MODEL / 8 + 255) / 256), blk, 0, stream>>>(Wo, wob, D_MODEL * D_MODEL, fIn);
    cast_bf16_kernel<<<dim3((D_FF * D_MODEL / 8 + 255) / 256), blk, 0, stream>>>(W1, w1b, D_FF * D_MODEL, fIn);
    // Flash attention over fused qkv
    flash_attn_kernel<<<dim3(BATCH * NHEAD * (SEQ / 64)), blk, 0, stream>>>(
        qkv, qkv + D_MODEL, qkv + 2 * D_MODEL, concat);
    // Output projection (BN=64 -> 512 blocks)
    gemm_mfma<2, false, false><<<dim3(D_MODEL / 64, M_TOK / 128), blk, 0, stream>>>(
        concat, wob, bo, bo, bo, D_MODEL, D_MODEL, proj, D_MODEL, D_MODEL, fIn);
    // Residual + LN1
    add_ln_kernel<false><<<dim3(M_TOK), blk, 0, stream>>>(x, proj, g1, be1, hb, fIn, fIn);
    // FFN1 (BN=128 -> 1024 blocks, ReLU)
    gemm_mfma<4, true, false><<<dim3(D_FF / 128, M_TOK / 128), blk, 0, stream>>>(
        hb, w1b, b1, b1, b1, D_FF, D_FF, ffn1, D_FF, D_MODEL, fIn);
    // FFN2 (BN=64 -> 512 blocks; W2 stays original dtype, dual-staged)
    gemm_mfma<2, false, true><<<dim3(D_MODEL / 64, M_TOK / 128), blk, 0, stream>>>(
        ffn1, W2, b2, b2, b2, D_MODEL, D_MODEL, ffn2, D_MODEL, D_FF, fIn);
    // Residual + LN2 -> fp32 output
    add_ln_kernel<true><<<dim3(M_TOK), blk, 0, stream>>>(hb, ffn2, g2, be2, d_out, fBf, fIn);
}

// Round 9
// 399.855 us; speedup vs baseline: 11.6290x; 1.2039x over previous
//
#include <hip/hip_runtime.h>
#include <hip/hip_bf16.h>

#define D_MODEL 1024
#define NHEAD 16
#define D_HEAD 64
#define D_FF 4096
#define BATCH 2
#define SEQ 2048
#define M_TOK (BATCH * SEQ)   // 4096 rows
#define EPS 1e-5f
#define QKV_N 3072

using bf16 = __hip_bfloat16;
typedef __attribute__((ext_vector_type(8))) short short8;
typedef __attribute__((ext_vector_type(4))) float float4v;

__device__ __forceinline__ float b2f(unsigned short u) {
    union { unsigned int i; float f; } v; v.i = ((unsigned int)u) << 16; return v.f;
}
__device__ __forceinline__ unsigned short f2b(float f) {   // RNE f32->bf16
    union { float f; unsigned int u; } v; v.f = f;
    unsigned int r = v.u + 0x7FFFu + ((v.u >> 16) & 1u);
    return (unsigned short)(r >> 16);
}
__device__ __forceinline__ float loadAt(const void* p, size_t i, int f32) {
    if (f32) return ((const float*)p)[i];
    return b2f(((const unsigned short*)p)[i]);
}
// Async global->LDS, 16 bytes per lane. LDS dest = wave-uniform base + lane*16.
__device__ __forceinline__ void async16(const void* g, void* lds) {
    __builtin_amdgcn_global_load_lds(
        (const __attribute__((address_space(1))) unsigned int*)g,
        (__attribute__((address_space(3))) unsigned int*)lds, 16, 0, 0);
}

// ---------------------------------------------------------------------------
__global__ void detect_kernel(const unsigned short* __restrict__ x, int* __restrict__ flag) {
    __shared__ int cnt;
    if (threadIdx.x == 0) cnt = 0;
    __syncthreads();
    int c = 0;
    for (int i = threadIdx.x; i < 8192; i += 256) {
        unsigned short u = x[i];
        int e = (u >> 7) & 0xFF;
        if (e >= 0xF0) c++;
    }
    atomicAdd(&cnt, c);
    __syncthreads();
    if (threadIdx.x == 0) { flag[0] = (cnt > 16) ? 1 : 0; flag[1] = 0; }
}

// ---------------------------------------------------------------------------
__global__ __launch_bounds__(256) void cast_bf16_kernel(
    const void* __restrict__ src, bf16* __restrict__ dst, int n,
    const int* __restrict__ flagp) {
    const int f32 = *flagp;
    int i0 = (blockIdx.x * 256 + threadIdx.x) * 8;
    if (i0 >= n) return;
    short8 v;
    if (f32) {
        const float* pf = (const float*)src + i0;
        float4v f0 = *(const float4v*)pf;
        float4v f1 = *(const float4v*)(pf + 4);
#pragma unroll
        for (int i = 0; i < 4; i++) { v[i] = (short)f2b(f0[i]); v[4 + i] = (short)f2b(f1[i]); }
    } else {
        v = *(const short8*)((const short*)src + i0);
    }
    *(short8*)((short*)dst + i0) = v;
}

// ---------------------------------------------------------------------------
// Cast 3 equal-size sources (2^20 els each) into one contiguous bf16 dst.
// ---------------------------------------------------------------------------
__global__ __launch_bounds__(256) void cast3_bf16_kernel(
    const void* __restrict__ s0, const void* __restrict__ s1,
    const void* __restrict__ s2, bf16* __restrict__ dst,
    const int* __restrict__ flagp) {
    const int f32 = *flagp;
    int i0 = (blockIdx.x * 256 + threadIdx.x) * 8;
    const int part = i0 >> 20;
    const int off = i0 & ((1 << 20) - 1);
    const void* src = (part == 0) ? s0 : (part == 1) ? s1 : s2;
    short8 v;
    if (f32) {
        const float* pf = (const float*)src + off;
        float4v f0 = *(const float4v*)pf;
        float4v f1 = *(const float4v*)(pf + 4);
#pragma unroll
        for (int i = 0; i < 4; i++) { v[i] = (short)f2b(f0[i]); v[4 + i] = (short)f2b(f1[i]); }
    } else {
        v = *(const short8*)((const short*)src + off);
    }
    *(short8*)((short*)dst + i0) = v;
}

// ---------------------------------------------------------------------------
__device__ __forceinline__ void stage8(const void* src, size_t off, int f32, short* dst) {
    short8 v;
    if (f32) {
        const float* pf = (const float*)src + off;
        float4v f0 = *(const float4v*)pf;
        float4v f1 = *(const float4v*)(pf + 4);
#pragma unroll
        for (int i = 0; i < 4; i++) { v[i] = (short)f2b(f0[i]); v[4 + i] = (short)f2b(f1[i]); }
    } else {
        v = *(const short8*)((const short*)src + off);
    }
    *(short8*)dst = v;
}

// ---------------------------------------------------------------------------
// MFMA GEMM v2: BK=64, 128B LDS rows, XOR chunk swizzle (slot = chunk^(row&7))
// -> conflict-free fragment reads while keeping global_load_lds contiguity.
// 4 waves as 2x2; wave computes MF*16 x NF*16; BM=32*MF, BN=32*NF.
// Configs: MF=NF=4 (128x128 tile) and MF=NF=2 (64x64 tile, 4 blocks/CU).
// BDYN: B staged via VGPR dual-dtype (fp32 W2 fallback; NF==2 only).
// ---------------------------------------------------------------------------
template <int MF, int NF, bool RELU, bool BDYN>
__global__ __launch_bounds__(256) void gemm_mfma(
    const bf16* __restrict__ A, const void* __restrict__ B,
    const void* __restrict__ bias0, const void* __restrict__ bias1,
    const void* __restrict__ bias2, int nb1, int nb2,
    bf16* __restrict__ C, int N, int K, const int* __restrict__ inFlagp) {
    constexpr int BM = 32 * MF, BN = 32 * NF;
    __shared__ short As[BM * 64];
    __shared__ short Bs[BN * 64];
    const int tid = threadIdx.x;
    const int lane = tid & 63;
    const int wv = tid >> 6;
    const int wm = wv & 1, wn = wv >> 1;
    const int quad = lane >> 4, lrow = lane & 15;
    const int rowM = blockIdx.y * BM;
    const int rowN = blockIdx.x * BN;
    const int inf = *inFlagp;

    float4v acc[MF][NF];
    const float4v zero = {0.f, 0.f, 0.f, 0.f};
#pragma unroll
    for (int i = 0; i < MF; i++)
#pragma unroll
        for (int j = 0; j < NF; j++) acc[i][j] = zero;

    // Async staging map: round rd covers 32 rows; wave wv covers 8 of them.
    // Lane l: row-in-round = wv*8 + (l>>3); LDS slot chunk = l&7;
    // global chunk g = slot ^ (rowLocal & 7) = (l&7) ^ (l>>3).
    const int sRow = lane >> 3;
    const int gChunk = (lane & 7) ^ sRow;

    for (int k0 = 0; k0 < K; k0 += 64) {
#pragma unroll
        for (int rd = 0; rd < MF; rd++) {
            const short* gp = (const short*)A +
                (size_t)(rowM + rd * 32 + wv * 8 + sRow) * K + k0 + gChunk * 8;
            async16(gp, &As[rd * 2048 + wv * 512]);
        }
        if (!BDYN) {
#pragma unroll
            for (int rd = 0; rd < NF; rd++) {
                const short* gp = (const short*)B +
                    (size_t)(rowN + rd * 32 + wv * 8 + sRow) * K + k0 + gChunk * 8;
                async16(gp, &Bs[rd * 2048 + wv * 512]);
            }
        } else {
            // NF==2: BN=64 rows x 8 chunks; thread stages 2 chunks of one row.
            const int brow = tid >> 2;
            const int c0 = (tid & 3) * 2;
#pragma unroll
            for (int cc = 0; cc < 2; cc++) {
                int slot = c0 + cc;
                int g = slot ^ (brow & 7);
                stage8(B, (size_t)(rowN + brow) * K + k0 + g * 8, inf,
                       &Bs[brow * 64 + slot * 8]);
            }
        }
        __syncthreads();
#pragma unroll
        for (int ks = 0; ks < 2; ks++) {
            short8 a_frag[MF], b_frag[NF];
#pragma unroll
            for (int i = 0; i < MF; i++) {
                const int row = wm * MF * 16 + i * 16 + lrow;
                const int slot = (ks * 4 + quad) ^ (row & 7);
                a_frag[i] = *(const short8*)&As[row * 64 + slot * 8];
            }
#pragma unroll
            for (int j = 0; j < NF; j++) {
                const int row = wn * NF * 16 + j * 16 + lrow;
                const int slot = (ks * 4 + quad) ^ (row & 7);
                b_frag[j] = *(const short8*)&Bs[row * 64 + slot * 8];
            }
#pragma unroll
            for (int i = 0; i < MF; i++)
#pragma unroll
                for (int j = 0; j < NF; j++)
                    acc[i][j] = __builtin_amdgcn_mfma_f32_16x16x32_bf16(
                        a_frag[i], b_frag[j], acc[i][j], 0, 0, 0);
        }
        __syncthreads();
    }

    const int mB = rowM + wm * MF * 16, nB = rowN + wn * NF * 16;
    unsigned short* Cu = (unsigned short*)C;
#pragma unroll
    for (int j = 0; j < NF; j++) {
        const int col = nB + j * 16 + lrow;
        float bv;
        if (col < nb1)      bv = loadAt(bias0, col, inf);
        else if (col < nb2) bv = loadAt(bias1, col - nb1, inf);
        else                bv = loadAt(bias2, col - nb2, inf);
#pragma unroll
        for (int i = 0; i < MF; i++) {
#pragma unroll
            for (int r = 0; r < 4; r++) {
                const int rowg = mB + i * 16 + quad * 4 + r;
                float vv = acc[i][j][r] + bv;
                if (RELU) vv = fmaxf(vv, 0.0f);
                Cu[(size_t)rowg * N + col] = f2b(vv);
            }
        }
    }
}

// ---------------------------------------------------------------------------
// MFMA flash attention, fixed-max softmax (R8-verified).
// ---------------------------------------------------------------------------
#define ASTRIDE 68
__global__ __launch_bounds__(256) void flash_attn_kernel(
    const bf16* __restrict__ Qb, const bf16* __restrict__ Kb,
    const bf16* __restrict__ Vb, bf16* __restrict__ O) {
    const int bid = blockIdx.x;
    const int qt = bid & 31;
    const int h  = (bid >> 5) & 15;
    const int b  = bid >> 9;
    const int q0 = qt * 64;
    const int tid = threadIdx.x;
    const int lane = tid & 63;
    const int wv = tid >> 6;
    const int quad = lane >> 4, lrow = lane & 15;

    __shared__ short Ks[64 * ASTRIDE];
    __shared__ short Vt[64 * ASTRIDE];
    __shared__ short Ps[64 * ASTRIDE];

    const size_t headOff = (size_t)h * D_HEAD;
    const float SC = 0.18033688f;    // 0.125 * log2(e)
    const float M2 = 23.0831204f;    // 16 * log2(e)

    {
        int r = tid >> 2, c0 = (tid & 3) * 16;
        const short* src = (const short*)Qb + (size_t)(b * SEQ + q0 + r) * QKV_N + headOff + c0;
        *(short8*)&Ps[r * ASTRIDE + c0]     = *(const short8*)src;
        *(short8*)&Ps[r * ASTRIDE + c0 + 8] = *(const short8*)(src + 8);
    }
    __syncthreads();
    short8 a_q[2];
    a_q[0] = *(const short8*)&Ps[(wv * 16 + lrow) * ASTRIDE + 0 * 32 + quad * 8];
    a_q[1] = *(const short8*)&Ps[(wv * 16 + lrow) * ASTRIDE + 1 * 32 + quad * 8];

    float4v o_acc[4];
    const float4v zero = {0.f, 0.f, 0.f, 0.f};
#pragma unroll
    for (int dt = 0; dt < 4; dt++) o_acc[dt] = zero;
    float lsum[4] = {0.f, 0.f, 0.f, 0.f};

    for (int j0 = 0; j0 < SEQ; j0 += 64) {
        __syncthreads();
        {
            int r = tid >> 2, c0 = (tid & 3) * 16;
            const short* src = (const short*)Kb + (size_t)(b * SEQ + j0 + r) * QKV_N + headOff + c0;
            *(short8*)&Ks[r * ASTRIDE + c0]     = *(const short8*)src;
            *(short8*)&Ks[r * ASTRIDE + c0 + 8] = *(const short8*)(src + 8);
        }
        {
            int jp = (tid & 31) * 2, d0 = (tid >> 5) * 8;
            const short* s0 = (const short*)Vb + (size_t)(b * SEQ + j0 + jp) * QKV_N + headOff + d0;
            short8 v0 = *(const short8*)s0;
            short8 v1 = *(const short8*)(s0 + QKV_N);
#pragma unroll
            for (int e = 0; e < 8; e++) {
                unsigned int w = (unsigned int)(unsigned short)v0[e] |
                                 ((unsigned int)(unsigned short)v1[e] << 16);
                *(unsigned int*)&Vt[(d0 + e) * ASTRIDE + jp] = w;
            }
        }
        __syncthreads();

        float4v s_acc[4];
#pragma unroll
        for (int jn = 0; jn < 4; jn++) s_acc[jn] = zero;
#pragma unroll
        for (int ks = 0; ks < 2; ks++)
#pragma unroll
            for (int jn = 0; jn < 4; jn++) {
                short8 bfr = *(const short8*)&Ks[(jn * 16 + lrow) * ASTRIDE + ks * 32 + quad * 8];
                s_acc[jn] = __builtin_amdgcn_mfma_f32_16x16x32_bf16(a_q[ks], bfr, s_acc[jn], 0, 0, 0);
            }

        float p[4][4];
#pragma unroll
        for (int r = 0; r < 4; r++) {
            float ls = 0.f;
#pragma unroll
            for (int jn = 0; jn < 4; jn++) {
                float pv = exp2f(fmaf(s_acc[jn][r], SC, -M2));
                p[jn][r] = pv;
                ls += pv;
            }
            lsum[r] += ls;
        }

#pragma unroll
        for (int jn = 0; jn < 4; jn++)
#pragma unroll
            for (int r = 0; r < 4; r++)
                Ps[(wv * 16 + quad * 4 + r) * ASTRIDE + jn * 16 + lrow] = (short)f2b(p[jn][r]);
        __syncthreads();

#pragma unroll
        for (int ks = 0; ks < 2; ks++) {
            short8 pa = *(const short8*)&Ps[(wv * 16 + lrow) * ASTRIDE + ks * 32 + quad * 8];
#pragma unroll
            for (int dt = 0; dt < 4; dt++) {
                short8 vb = *(const short8*)&Vt[(dt * 16 + lrow) * ASTRIDE + ks * 32 + quad * 8];
                o_acc[dt] = __builtin_amdgcn_mfma_f32_16x16x32_bf16(pa, vb, o_acc[dt], 0, 0, 0);
            }
        }
    }

    float invl[4];
#pragma unroll
    for (int r = 0; r < 4; r++) {
        float t = lsum[r];
        t += __shfl_xor(t, 1);
        t += __shfl_xor(t, 2);
        t += __shfl_xor(t, 4);
        t += __shfl_xor(t, 8);
        invl[r] = 1.0f / t;
    }
    unsigned short* Ou = (unsigned short*)O;
#pragma unroll
    for (int dt = 0; dt < 4; dt++)
#pragma unroll
        for (int r = 0; r < 4; r++) {
            const int rowg = b * SEQ + q0 + wv * 16 + quad * 4 + r;
            Ou[(size_t)rowg * D_MODEL + headOff + dt * 16 + lrow] = f2b(o_acc[dt][r] * invl[r]);
        }
}

// ---------------------------------------------------------------------------
template <bool OUT_F32>
__global__ __launch_bounds__(256) void add_ln_kernel(
    const void* __restrict__ X, const bf16* __restrict__ R,
    const void* __restrict__ g, const void* __restrict__ be,
    void* __restrict__ Y,
    const int* __restrict__ xFlagp, const int* __restrict__ wFlagp) {
    const int xf = *xFlagp;
    const int wf = *wFlagp;
    const int row = blockIdx.x;
    const size_t base = (size_t)row * D_MODEL;
    const int tid = threadIdx.x;
    __shared__ float red[256];
    float v[4];
#pragma unroll
    for (int i = 0; i < 4; i++) {
        int idx = tid + i * 256;
        v[i] = loadAt(X, base + idx, xf) + __bfloat162float(R[base + idx]);
    }
    float s = v[0] + v[1] + v[2] + v[3];
    red[tid] = s; __syncthreads();
    for (int s2 = 128; s2 > 0; s2 >>= 1) {
        if (tid < s2) red[tid] += red[tid + s2];
        __syncthreads();
    }
    float mu = red[0] * (1.0f / D_MODEL);
    __syncthreads();
    float s2v = 0.f;
#pragma unroll
    for (int i = 0; i < 4; i++) { float dd = v[i] - mu; s2v += dd * dd; }
    red[tid] = s2v; __syncthreads();
    for (int s2 = 128; s2 > 0; s2 >>= 1) {
        if (tid < s2) red[tid] += red[tid + s2];
        __syncthreads();
    }
    float rstd = rsqrtf(red[0] * (1.0f / D_MODEL) + EPS);
    __syncthreads();
#pragma unroll
    for (int i = 0; i < 4; i++) {
        int idx = tid + i * 256;
        float o = (v[i] - mu) * rstd * loadAt(g, idx, wf) + loadAt(be, idx, wf);
        if (OUT_F32) ((float*)Y)[base + idx] = o;
        else         ((bf16*)Y)[base + idx] = __float2bfloat16(o);
    }
}

// ---------------------------------------------------------------------------
extern "C" void kernel_launch(void* const* d_in, const int* in_sizes, int n_in,
                              void* d_out, int out_size, void* d_ws, size_t ws_size,
                              hipStream_t stream) {
    const void* x  = d_in[0];
    const void* Wq = d_in[1];  const void* bq = d_in[2];
    const void* Wk = d_in[3];  const void* bk = d_in[4];
    const void* Wv = d_in[5];  const void* bv = d_in[6];
    const void* Wo = d_in[7];  const void* bo = d_in[8];
    const void* W1 = d_in[9];  const void* b1 = d_in[10];
    const void* W2 = d_in[11]; const void* b2 = d_in[12];
    const void* g1 = d_in[13]; const void* be1 = d_in[14];
    const void* g2 = d_in[15]; const void* be2 = d_in[16];

    char* ws = (char*)d_ws;
    const size_t MB = 1024 * 1024;
    // Proven R7/R8 choreography (48 MB core):
    bf16* xb     = (bf16*)(ws + 0 * MB);
    bf16* wqkvb  = (bf16*)(ws + 8 * MB);
    bf16* wob    = (bf16*)(ws + 14 * MB);
    bf16* qkv    = (bf16*)(ws + 16 * MB);
    bf16* concat = (bf16*)(ws + 40 * MB);
    bf16* w1b    = (bf16*)(ws + 0 * MB);
    bf16* proj   = (bf16*)(ws + 16 * MB);
    bf16* hb     = (bf16*)(ws + 8 * MB);
    bf16* ffn1   = (bf16*)(ws + 16 * MB);
    bf16* ffn2   = (bf16*)(ws + 0 * MB);
    // Optional W2 pre-cast region [48..56) if the workspace is big enough.
    const bool castW2 = (ws_size >= 56 * MB + 8);
    bf16* w2b    = (bf16*)(ws + 48 * MB);
    int*  flag   = (int*)(ws + (castW2 ? 56 * MB : 48 * MB));

    const int* fIn = flag;
    const int* fBf = flag + 1;

    dim3 blk(256);

    detect_kernel<<<dim3(1), blk, 0, stream>>>((const unsigned short*)x, flag);
    // Pre-casts
    cast_bf16_kernel<<<dim3((M_TOK * D_MODEL / 8 + 255) / 256), blk, 0, stream>>>(x, xb, M_TOK * D_MODEL, fIn);
    cast3_bf16_kernel<<<dim3(3 * D_MODEL * D_MODEL / 8 / 256), blk, 0, stream>>>(Wq, Wk, Wv, wqkvb, fIn);
    if (castW2)
        cast_bf16_kernel<<<dim3((D_FF * D_MODEL / 8 + 255) / 256), blk, 0, stream>>>(W2, w2b, D_FF * D_MODEL, fIn);
    // Fused QKV projection: [4096,3072], 128x128 tiles -> 768 blocks
    gemm_mfma<4, 4, false, false><<<dim3(QKV_N / 128, M_TOK / 128), blk, 0, stream>>>(
        xb, wqkvb, bq, bk, bv, 1024, 2048, qkv, QKV_N, D_MODEL, fIn);
    // Cast Wo/W1 into regions freed by xb/wqkvb
    cast_bf16_kernel<<<dim3((D_MODEL * D_MODEL / 8 + 255) / 256), blk, 0, stream>>>(Wo, wob, D_MODEL * D_MODEL, fIn);
    cast_bf16_kernel<<<dim3((D_FF * D_MODEL / 8 + 255) / 256), blk, 0, stream>>>(W1, w1b, D_FF * D_MODEL, fIn);
    // Flash attention
    flash_attn_kernel<<<dim3(BATCH * NHEAD * (SEQ / 64)), blk, 0, stream>>>(
        qkv, qkv + D_MODEL, qkv + 2 * D_MODEL, concat);
    // Output projection: 64x64 tiles -> 1024 blocks (4/CU)
    gemm_mfma<2, 2, false, false><<<dim3(D_MODEL / 64, M_TOK / 64), blk, 0, stream>>>(
        concat, wob, bo, bo, bo, D_MODEL, D_MODEL, proj, D_MODEL, D_MODEL, fIn);
    // Residual + LN1
    add_ln_kernel<false><<<dim3(M_TOK), blk, 0, stream>>>(x, proj, g1, be1, hb, fIn, fIn);
    // FFN1: 128x128 tiles -> 1024 blocks, ReLU
    gemm_mfma<4, 4, true, false><<<dim3(D_FF / 128, M_TOK / 128), blk, 0, stream>>>(
        hb, w1b, b1, b1, b1, D_FF, D_FF, ffn1, D_FF, D_MODEL, fIn);
    // FFN2: 64x64 tiles -> 1024 blocks; bf16 W2 if pre-cast else dual-dtype
    if (castW2)
        gemm_mfma<2, 2, false, false><<<dim3(D_MODEL / 64, M_TOK / 64), blk, 0, stream>>>(
            ffn1, w2b, b2, b2, b2, D_MODEL, D_MODEL, ffn2, D_MODEL, D_FF, fIn);
    else
        gemm_mfma<2, 2, false, true><<<dim3(D_MODEL / 64, M_TOK / 64), blk, 0, stream>>>(
            ffn1, W2, b2, b2, b2, D_MODEL, D_MODEL, ffn2, D_MODEL, D_FF, fIn);
    // Residual + LN2 -> fp32 output
    add_ln_kernel<true><<<dim3(M_TOK), blk, 0, stream>>>(hb, ffn2, g2, be2, d_out, fBf, fIn);
}